// Round 9
// baseline (155.983 us; speedup 1.0000x reference)
//
#include <hip/hip_runtime.h>

typedef _Float16 half8_t __attribute__((ext_vector_type(8)));
typedef _Float16 half4_t __attribute__((ext_vector_type(4)));
typedef _Float16 half2_t __attribute__((ext_vector_type(2)));
typedef __fp16 fp16x2 __attribute__((ext_vector_type(2)));
typedef float f32x4 __attribute__((ext_vector_type(4)));

#define S_LEN 2048
#define D_DIM 64
#define SD (S_LEN * D_DIM)
#define LDK 72             // fallback kernel: f16 row stride
#define LDO 68             // f32 row stride for epilogue
#define THR 4.0f           // lazy-max threshold: stale-path P <= 2^4
#define WS_NEED ((size_t)(16 * 1024 * 1024 + 16384))

// ============================================================================
// PREP (once; round-6 version, proven): K -> swizzled f16 8KB tiles; V ->
// transposed, swizzled f16 8KB tiles with MASKED ROWS ZEROED; keep[] -> f16.
// K tile: byte(row,16B-gran j) = row*128 + ((16j) ^ ((row&7)<<4))
// V tile: byte(drow,8B-gran j2) = drow*128 + ((8j2) ^ ((drow&15)<<3))
// ============================================================================
__global__ __launch_bounds__(256)
void prep_kernel(const float* __restrict__ Kg, const float* __restrict__ Vg,
                 const int* __restrict__ Mg, _Float16* __restrict__ wsK,
                 _Float16* __restrict__ wsV, _Float16* __restrict__ wsKeep) {
  __shared__ float vt[64][68];
  const int blk = blockIdx.x;   // [0,1024) K; [1024,2048) V; [2048,2052) keep
  const int t = threadIdx.x;

  if (blk < 1024) {
    const int bh = blk >> 5, kt = blk & 31;
    const float* src = Kg + (size_t)bh * SD + (size_t)kt * 64 * D_DIM;
    char* dst = (char*)wsK + (size_t)blk * 8192;
#pragma unroll
    for (int i = 0; i < 2; ++i) {
      int task = t + 256 * i;        // 512 granules: row 0..63 x j 0..7
      int row = task >> 3, j = task & 7;
      float4 lo = *(const float4*)(src + row * D_DIM + 8 * j);
      float4 hi = *(const float4*)(src + row * D_DIM + 8 * j + 4);
      fp16x2 p0 = __builtin_amdgcn_cvt_pkrtz(lo.x, lo.y);
      fp16x2 p1 = __builtin_amdgcn_cvt_pkrtz(lo.z, lo.w);
      fp16x2 p2 = __builtin_amdgcn_cvt_pkrtz(hi.x, hi.y);
      fp16x2 p3 = __builtin_amdgcn_cvt_pkrtz(hi.z, hi.w);
      half8_t h;
      h[0] = (_Float16)p0[0]; h[1] = (_Float16)p0[1];
      h[2] = (_Float16)p1[0]; h[3] = (_Float16)p1[1];
      h[4] = (_Float16)p2[0]; h[5] = (_Float16)p2[1];
      h[6] = (_Float16)p3[0]; h[7] = (_Float16)p3[1];
      *(half8_t*)(dst + row * 128 + ((16 * j) ^ ((row & 7) << 4))) = h;
    }
  } else if (blk < 2048) {
    const int vb = blk - 1024;
    const int bh = vb >> 5, kt = vb & 31;
    const float* src = Vg + (size_t)bh * SD + (size_t)kt * 64 * D_DIM;
    const int* msk = Mg + (size_t)(bh >> 3) * S_LEN + kt * 64;
#pragma unroll
    for (int i = 0; i < 4; ++i) {
      int r = (t >> 4) + 16 * i, c4 = t & 15;
      *(float4*)&vt[r][c4 * 4] = *(const float4*)(src + r * D_DIM + c4 * 4);
    }
    __syncthreads();
    char* dst = (char*)wsV + (size_t)vb * 8192;
#pragma unroll
    for (int i = 0; i < 4; ++i) {
      int task = t + 256 * i;        // 1024 granules: drow 0..63 x j2 0..15
      int drow = task >> 4, j2 = task & 15, k0 = 4 * j2;
      int4 mv = *(const int4*)(msk + k0);
      float a  = vt[k0][drow]     * (float)mv.x;
      float b  = vt[k0 + 1][drow] * (float)mv.y;
      float cc = vt[k0 + 2][drow] * (float)mv.z;
      float d  = vt[k0 + 3][drow] * (float)mv.w;
      fp16x2 h0 = __builtin_amdgcn_cvt_pkrtz(a, b);
      fp16x2 h1 = __builtin_amdgcn_cvt_pkrtz(cc, d);
      half4_t h;
      h[0] = (_Float16)h0[0]; h[1] = (_Float16)h0[1];
      h[2] = (_Float16)h1[0]; h[3] = (_Float16)h1[1];
      *(half4_t*)(dst + drow * 128 + ((8 * j2) ^ ((drow & 15) << 3))) = h;
    }
  } else {
    const int b = blk - 2048;      // batch
    const int* src = Mg + (size_t)b * S_LEN + 8 * t;
    int4 m0 = *(const int4*)src;
    int4 m1 = *(const int4*)(src + 4);
    half8_t h;
    h[0] = (_Float16)(float)m0.x; h[1] = (_Float16)(float)m0.y;
    h[2] = (_Float16)(float)m0.z; h[3] = (_Float16)(float)m0.w;
    h[4] = (_Float16)(float)m1.x; h[5] = (_Float16)(float)m1.y;
    h[6] = (_Float16)(float)m1.z; h[7] = (_Float16)(float)m1.w;
    *(half8_t*)(wsKeep + (size_t)b * S_LEN + 8 * t) = h;
  }
}

// ============================================================================
// MAIN: R8 body + T4 counted-vmcnt pipeline. QUAD-buffered K/V (4x16KB),
// DMA issued TWO tiles ahead; per-iter sync is
//   issue dma(kt+2) -> s_waitcnt vmcnt(8) -> raw s_barrier
// vmcnt(8) waits only the OLDEST 4 loads (= dma(kt)) while dma(kt+1) and
// dma(kt+2) stay in flight (m135 in-order semantics); producer-wait BEFORE
// the barrier makes cross-wave LDS writes visible; 4 buffers put 2 barriers
// between a buffer's last read and its overwrite -> race-free early issue.
// Never vmcnt(0) in the loop (R8's __syncthreads drained everything each
// iter -- the barrier-drain stall). LDS 64KB -> 2 blocks/CU (8 waves),
// which also halves R8's LDS-read traffic (the ~63%-busy pipe) per CU.
// ============================================================================
__global__ __launch_bounds__(256, 2)
void fattn_dma(const float* __restrict__ Qg, const _Float16* __restrict__ wsK,
               const _Float16* __restrict__ wsV,
               const _Float16* __restrict__ wsKeep, float* __restrict__ Og) {
  __shared__ __align__(16) char smem[65536];
  // K bufs 4x8192 [0,32768); V bufs 4x8192 [32768,65536)
  float* Osh = (float*)smem;   // epilogue reuse (17408B; only overlaps K buf0/1,
                               // dead by then — last iters read bufs 2,3)

  const int t = threadIdx.x;
  const int w = t >> 6;
  const int lane = t & 63;
  const int g = lane >> 4;
  const int c = lane & 15;

  const int bh = blockIdx.x & 31;   // bh fast: ws pinned to one XCD's L2
  const int qt = blockIdx.x >> 5;
  const int qb = qt * 64;           // 64 q-rows per block, 16 per wave

  const float* Qb = Qg + (size_t)bh * SD;
  float*       Ob = Og + (size_t)bh * SD;
  const _Float16* keepB = wsKeep + (size_t)(bh >> 3) * S_LEN;  // H = 8

  // ---- Q^T B-frags for q = qb + 16w + c; fold 1/8 * log2(e) ----
  const float qscale = 0.125f * 1.44269504088896340736f;
  half8_t qf[2];
  {
    const float* qp = Qb + (size_t)(qb + 16 * w + c) * D_DIM + 8 * g;
#pragma unroll
    for (int ks = 0; ks < 2; ++ks) {
      float4 lo = *(const float4*)(qp + 32 * ks);
      float4 hi = *(const float4*)(qp + 32 * ks + 4);
      fp16x2 p0 = __builtin_amdgcn_cvt_pkrtz(lo.x * qscale, lo.y * qscale);
      fp16x2 p1 = __builtin_amdgcn_cvt_pkrtz(lo.z * qscale, lo.w * qscale);
      fp16x2 p2 = __builtin_amdgcn_cvt_pkrtz(hi.x * qscale, hi.y * qscale);
      fp16x2 p3 = __builtin_amdgcn_cvt_pkrtz(hi.z * qscale, hi.w * qscale);
      half8_t hh;
      hh[0] = (_Float16)p0[0]; hh[1] = (_Float16)p0[1];
      hh[2] = (_Float16)p1[0]; hh[3] = (_Float16)p1[1];
      hh[4] = (_Float16)p2[0]; hh[5] = (_Float16)p2[1];
      hh[6] = (_Float16)p3[0]; hh[7] = (_Float16)p3[1];
      qf[ks] = hh;
    }
  }

  // ---- DMA staging: per wave 2KB K + 2KB V (exactly 4 x 16B/lane issues,
  //      so vmcnt counts 4 per dma) ----
  const size_t tbase = (size_t)bh * 262144;
  auto dma = [&](int buf, int kt) {
    const char* gK = (const char*)wsK + tbase + (size_t)kt * 8192 +
                     w * 2048 + lane * 16;
    const char* gV = (const char*)wsV + tbase + (size_t)kt * 8192 +
                     w * 2048 + lane * 16;
    char* lK = smem + 8192 * buf + w * 2048;
    char* lV = smem + 32768 + 8192 * buf + w * 2048;
    __builtin_amdgcn_global_load_lds((const float*)gK, (float*)lK, 16, 0, 0);
    __builtin_amdgcn_global_load_lds((const float*)(gK + 1024),
                                     (float*)(lK + 1024), 16, 0, 0);
    __builtin_amdgcn_global_load_lds((const float*)gV, (float*)lV, 16, 0, 0);
    __builtin_amdgcn_global_load_lds((const float*)(gV + 1024),
                                     (float*)(lV + 1024), 16, 0, 0);
  };

  f32x4 acc[4];
  f32x4 accl;
#pragma unroll
  for (int j = 0; j < 4; ++j) {
    accl[j] = 0.f;
#pragma unroll
    for (int i = 0; i < 4; ++i) acc[i][j] = 0.f;
  }
  float mrun = -1e30f;

  const int kxor = (c & 7) << 4;
  const int vxor = c << 3;

  // prologue: tiles 0 and 1 in flight (8 outstanding vmem/wave)
  dma(0, 0);
  dma(1, 1);

  for (int kt = 0; kt < 32; ++kt) {
    // issue dma(kt+2) (clamped; redundant tail loads land in dead buffers)
    dma((kt + 2) & 3, (kt + 2 > 31) ? 31 : kt + 2);
    // wait OLDEST 4 loads only (= dma(kt)); kt+1, kt+2 remain in flight
    asm volatile("s_waitcnt vmcnt(8)" ::: "memory");
    __builtin_amdgcn_s_barrier();   // all waves' dma(kt) now visible

    const char* Kc = smem + 8192 * (kt & 3);
    const char* Vc = smem + 32768 + 8192 * (kt & 3);

    // ---- keep A-frags for the l-MFMA (global b64, L2-hot) ----
    half4_t kA[4];
#pragma unroll
    for (int mt = 0; mt < 4; ++mt)
      kA[mt] = *(const half4_t*)(keepB + kt * 64 + 16 * mt + 4 * g);

    // ---- S^T = K . Q^T ----
    f32x4 sT[4];
    __builtin_amdgcn_s_setprio(1);
#pragma unroll
    for (int mt = 0; mt < 4; ++mt) {
      const char* Krow = Kc + (16 * mt + c) * 128;
      f32x4 z;
#pragma unroll
      for (int j = 0; j < 4; ++j) z[j] = 0.f;
#pragma unroll
      for (int ks = 0; ks < 2; ++ks) {
        half8_t kf = *(const half8_t*)(Krow + ((ks * 64 + g * 16) ^ kxor));
        z = __builtin_amdgcn_mfma_f32_16x16x32_f16(kf, qf[ks], z, 0, 0, 0);
      }
      sT[mt] = z;
    }
    __builtin_amdgcn_s_setprio(0);

    // ---- V A-frags (K=16 PV), issued before softmax to hide LDS latency ----
    half4_t vf[4][4];  // [d-tile][k-step]
#pragma unroll
    for (int dt = 0; dt < 4; ++dt)
#pragma unroll
      for (int mtk = 0; mtk < 4; ++mtk)
        vf[dt][mtk] = *(const half4_t*)(Vc + (16 * dt + c) * 128 +
                                        ((32 * mtk + 8 * g) ^ vxor));

    // ---- lazy raw-score max: no cross-lane in the common path ----
    float tl = -1e30f;
#pragma unroll
    for (int mt = 0; mt < 4; ++mt)
      tl = fmaxf(tl, fmaxf(fmaxf(sT[mt][0], sT[mt][1]),
                           fmaxf(sT[mt][2], sT[mt][3])));
    if (!__all(tl <= mrun + THR)) {
      // rare: exact row-max update + alpha rescale (wave-uniform branch)
      float tmax = fmaxf(tl, __shfl_xor(tl, 16));
      tmax = fmaxf(tmax, __shfl_xor(tmax, 32));
      float mnew = fmaxf(mrun, tmax);
      float alpha = __builtin_amdgcn_exp2f(mrun - mnew);
      mrun = mnew;
#pragma unroll
      for (int j = 0; j < 4; ++j) {
        accl[j] *= alpha;
#pragma unroll
        for (int i = 0; i < 4; ++i) acc[i][j] *= alpha;
      }
    }

    // ---- exp + in-register pack + PV; l-sum via keep-MFMA ----
    __builtin_amdgcn_s_setprio(1);
#pragma unroll
    for (int mt = 0; mt < 4; ++mt) {
      float pv0 = __builtin_amdgcn_exp2f(sT[mt][0] - mrun);
      float pv1 = __builtin_amdgcn_exp2f(sT[mt][1] - mrun);
      float pv2 = __builtin_amdgcn_exp2f(sT[mt][2] - mrun);
      float pv3 = __builtin_amdgcn_exp2f(sT[mt][3] - mrun);
      fp16x2 p01 = __builtin_amdgcn_cvt_pkrtz(pv0, pv1);
      fp16x2 p23 = __builtin_amdgcn_cvt_pkrtz(pv2, pv3);
      half4_t pf;
      pf[0] = (_Float16)p01[0]; pf[1] = (_Float16)p01[1];
      pf[2] = (_Float16)p23[0]; pf[3] = (_Float16)p23[1];
      accl = __builtin_amdgcn_mfma_f32_16x16x16f16(kA[mt], pf, accl, 0, 0, 0);
#pragma unroll
      for (int dt = 0; dt < 4; ++dt)
        acc[dt] = __builtin_amdgcn_mfma_f32_16x16x16f16(vf[dt][mt], pf,
                                                        acc[dt], 0, 0, 0);
    }
    __builtin_amdgcn_s_setprio(0);
    // no end-of-iter barrier: next iter's {waitcnt, barrier} is the sync
  }

  // ---- epilogue: /l, transpose O^T -> O via LDS, coalesced stores ----
  // Osh overlaps K bufs 0/1 only; last two iters read bufs 2/3, and the
  // final loop barrier guarantees all waves are past iter-30 reads.
  {
    float linv = 1.f / accl[0];   // keep-MFMA replicates l over rows
#pragma unroll
    for (int mt = 0; mt < 4; ++mt)
#pragma unroll
      for (int r = 0; r < 4; ++r)
        Osh[(16 * w + c) * LDO + 16 * mt + 4 * g + r] = acc[mt][r] * linv;
  }
  __syncthreads();
  {
    int f8 = t & 7;
#pragma unroll
    for (int i = 0; i < 2; ++i) {
      int q = (t >> 3) + 32 * i;
#pragma unroll
      for (int j = 0; j < 2; ++j) {
        int c4 = f8 + 8 * j;
        f32x4 o = *(f32x4*)(Osh + q * LDO + c4 * 4);
        *(float4*)(Ob + (size_t)(qb + q) * D_DIM + c4 * 4) =
            make_float4(o.x, o.y, o.z, o.w);
      }
    }
  }
}

// ============================================================================
// FALLBACK (round-3 kernel) — used only if ws_size < WS_NEED.
// ============================================================================
__global__ __launch_bounds__(256, 2)
void fattn_fb(const float* __restrict__ Qg, const float* __restrict__ Kg,
              const float* __restrict__ Vg, const int* __restrict__ Mg,
              float* __restrict__ Og) {
  __shared__ __align__(16) char smem[45056];
  float* Msh = (float*)(smem + 36864);
  float* Osh = (float*)smem;

  const int t = threadIdx.x;
  const int w = t >> 6;
  const int lane = t & 63;
  const int g = lane >> 4;
  const int c = lane & 15;

  const int bh = blockIdx.x & 31;
  const int qt = blockIdx.x >> 5;
  const int qb = qt * 128;

  const float* Qb = Qg + (size_t)bh * SD;
  const float* Kb = Kg + (size_t)bh * SD;
  const float* Vb = Vg + (size_t)bh * SD;
  const int*   Mb = Mg + (size_t)(bh >> 3) * S_LEN;
  float*       Ob = Og + (size_t)bh * SD;

  {
    int4 m0 = *(const int4*)(Mb + 8 * t);
    int4 m1 = *(const int4*)(Mb + 8 * t + 4);
    float4 f0, f1;
    f0.x = (float)(m0.x - 1) * 1e30f; f0.y = (float)(m0.y - 1) * 1e30f;
    f0.z = (float)(m0.z - 1) * 1e30f; f0.w = (float)(m0.w - 1) * 1e30f;
    f1.x = (float)(m1.x - 1) * 1e30f; f1.y = (float)(m1.y - 1) * 1e30f;
    f1.z = (float)(m1.z - 1) * 1e30f; f1.w = (float)(m1.w - 1) * 1e30f;
    *(float4*)(Msh + 8 * t) = f0;
    *(float4*)(Msh + 8 * t + 4) = f1;
  }

  const float qscale = 0.125f * 1.44269504088896340736f;
  half8_t qf[2][2];
#pragma unroll
  for (int h = 0; h < 2; ++h) {
    const float* qp = Qb + (size_t)(qb + 32 * w + 16 * h + c) * D_DIM + 8 * g;
#pragma unroll
    for (int ks = 0; ks < 2; ++ks) {
      float4 lo = *(const float4*)(qp + 32 * ks);
      float4 hi = *(const float4*)(qp + 32 * ks + 4);
      fp16x2 p0 = __builtin_amdgcn_cvt_pkrtz(lo.x * qscale, lo.y * qscale);
      fp16x2 p1 = __builtin_amdgcn_cvt_pkrtz(lo.z * qscale, lo.w * qscale);
      fp16x2 p2 = __builtin_amdgcn_cvt_pkrtz(hi.x * qscale, hi.y * qscale);
      fp16x2 p3 = __builtin_amdgcn_cvt_pkrtz(hi.z * qscale, hi.w * qscale);
      half8_t hh;
      hh[0] = (_Float16)p0[0]; hh[1] = (_Float16)p0[1];
      hh[2] = (_Float16)p1[0]; hh[3] = (_Float16)p1[1];
      hh[4] = (_Float16)p2[0]; hh[5] = (_Float16)p2[1];
      hh[6] = (_Float16)p3[0]; hh[7] = (_Float16)p3[1];
      qf[h][ks] = hh;
    }
  }

  const int krow0 = t >> 4;
  const int kc4   = t & 15;
  const int vp    = t >> 3;
  const int vkpl  = t & 7;

  float4 kr[4];
  float2 vr[8];
  auto prefetch = [&](int kb2) {
#pragma unroll
    for (int it = 0; it < 4; ++it)
      kr[it] = *(const float4*)(Kb + (size_t)(kb2 + krow0 + 16 * it) * D_DIM + kc4 * 4);
#pragma unroll
    for (int kc = 0; kc < 4; ++kc) {
      const float* vpp = Vb + (size_t)(kb2 + 2 * (vkpl + 8 * kc)) * D_DIM + 2 * vp;
      vr[2 * kc]     = *(const float2*)(vpp);
      vr[2 * kc + 1] = *(const float2*)(vpp + D_DIM);
    }
  };
  auto stage = [&](int buf) {
    _Float16* Kd = (_Float16*)(smem + 9216 * buf);
    _Float16* Vd = (_Float16*)(smem + 18432 + 9216 * buf);
#pragma unroll
    for (int it = 0; it < 4; ++it) {
      fp16x2 a  = __builtin_amdgcn_cvt_pkrtz(kr[it].x, kr[it].y);
      fp16x2 b2 = __builtin_amdgcn_cvt_pkrtz(kr[it].z, kr[it].w);
      half4_t h;
      h[0] = (_Float16)a[0]; h[1] = (_Float16)a[1];
      h[2] = (_Float16)b2[0]; h[3] = (_Float16)b2[1];
      *(half4_t*)(Kd + (krow0 + 16 * it) * LDK + kc4 * 4) = h;
    }
#pragma unroll
    for (int kc = 0; kc < 4; ++kc) {
      int kp = vkpl + 8 * kc;
      fp16x2 h0 = __builtin_amdgcn_cvt_pkrtz(vr[2 * kc].x, vr[2 * kc + 1].x);
      fp16x2 h1 = __builtin_amdgcn_cvt_pkrtz(vr[2 * kc].y, vr[2 * kc + 1].y);
      half2_t g0; g0[0] = (_Float16)h0[0]; g0[1] = (_Float16)h0[1];
      half2_t g1; g1[0] = (_Float16)h1[0]; g1[1] = (_Float16)h1[1];
      *(half2_t*)(Vd + (2 * vp) * LDK + 2 * kp) = g0;
      *(half2_t*)(Vd + (2 * vp + 1) * LDK + 2 * kp) = g1;
    }
  };

  f32x4 acc[2][4];
  f32x4 accl[2];
#pragma unroll
  for (int h = 0; h < 2; ++h) {
#pragma unroll
    for (int j = 0; j < 4; ++j) accl[h][j] = 0.f;
#pragma unroll
    for (int i = 0; i < 4; ++i)
#pragma unroll
      for (int j = 0; j < 4; ++j) acc[h][i][j] = 0.f;
  }
  float mrun[2] = {-1e30f, -1e30f};

  half4_t ones4;
  ones4[0] = (_Float16)1.0f; ones4[1] = (_Float16)1.0f;
  ones4[2] = (_Float16)1.0f; ones4[3] = (_Float16)1.0f;

  prefetch(0);
  stage(0);
  prefetch(64);
  __syncthreads();

  for (int kt = 0; kt < 32; ++kt) {
    const int kb = kt * 64;
    const int cur = kt & 1;

    if (kt < 31) stage(cur ^ 1);
    if (kt < 30) prefetch(kb + 128);

    const _Float16* Kc = (const _Float16*)(smem + 9216 * cur);
    const _Float16* Vc = (const _Float16*)(smem + 18432 + 9216 * cur);

    f32x4 sT[2][4];
    __builtin_amdgcn_s_setprio(1);
#pragma unroll
    for (int mt = 0; mt < 4; ++mt) {
      f32x4 z0, z1;
#pragma unroll
      for (int j = 0; j < 4; ++j) { z0[j] = 0.f; z1[j] = 0.f; }
#pragma unroll
      for (int ks = 0; ks < 2; ++ks) {
        half8_t kf = *(half8_t*)(Kc + (16 * mt + c) * LDK + ks * 32 + 8 * g);
        z0 = __builtin_amdgcn_mfma_f32_16x16x32_f16(kf, qf[0][ks], z0, 0, 0, 0);
        z1 = __builtin_amdgcn_mfma_f32_16x16x32_f16(kf, qf[1][ks], z1, 0, 0, 0);
      }
      sT[0][mt] = z0;
      sT[1][mt] = z1;
    }
    __builtin_amdgcn_s_setprio(0);

    half4_t vf[4][4];
#pragma unroll
    for (int dt = 0; dt < 4; ++dt)
#pragma unroll
      for (int kst = 0; kst < 4; ++kst)
        vf[dt][kst] = *(half4_t*)(Vc + (16 * dt + c) * LDK + 16 * kst + 4 * g);

    f32x4 mvf[4];
#pragma unroll
    for (int mt = 0; mt < 4; ++mt)
      mvf[mt] = *(const f32x4*)(Msh + kb + 16 * mt + 4 * g);
#pragma unroll
    for (int h = 0; h < 2; ++h)
#pragma unroll
      for (int mt = 0; mt < 4; ++mt)
#pragma unroll
        for (int r = 0; r < 4; ++r) sT[h][mt][r] += mvf[mt][r];

    float tl[2];
#pragma unroll
    for (int h = 0; h < 2; ++h) {
      float tm0 = fmaxf(fmaxf(sT[h][0][0], sT[h][0][1]),
                        fmaxf(sT[h][0][2], sT[h][0][3]));
      float tm1 = fmaxf(fmaxf(sT[h][1][0], sT[h][1][1]),
                        fmaxf(sT[h][1][2], sT[h][1][3]));
      float tm2 = fmaxf(fmaxf(sT[h][2][0], sT[h][2][1]),
                        fmaxf(sT[h][2][2], sT[h][2][3]));
      float tm3 = fmaxf(fmaxf(sT[h][3][0], sT[h][3][1]),
                        fmaxf(sT[h][3][2], sT[h][3][3]));
      tl[h] = fmaxf(fmaxf(tm0, tm1), fmaxf(tm2, tm3));
    }
    int ok0 = __all(tl[0] <= mrun[0] + THR);
    int ok1 = __all(tl[1] <= mrun[1] + THR);
    if (!(ok0 & ok1)) {
#pragma unroll
      for (int h = 0; h < 2; ++h) {
        float tmax = tl[h];
        tmax = fmaxf(tmax, __shfl_xor(tmax, 16));
        tmax = fmaxf(tmax, __shfl_xor(tmax, 32));
        float mnew = fmaxf(mrun[h], tmax);
        float alpha = __builtin_amdgcn_exp2f(mrun[h] - mnew);
        mrun[h] = mnew;
        accl[h][0] *= alpha; accl[h][1] *= alpha;
        accl[h][2] *= alpha; accl[h][3] *= alpha;
#pragma unroll
        for (int mt = 0; mt < 4; ++mt) {
          acc[h][mt][0] *= alpha; acc[h][mt][1] *= alpha;
          acc[h][mt][2] *= alpha; acc[h][mt][3] *= alpha;
        }
      }
    }

    __builtin_amdgcn_s_setprio(1);
#pragma unroll
    for (int h = 0; h < 2; ++h) {
#pragma unroll
      for (int mt = 0; mt < 4; ++mt) {
        float pv0 = __builtin_amdgcn_exp2f(sT[h][mt][0] - mrun[h]);
        float pv1 = __builtin_amdgcn_exp2f(sT[h][mt][1] - mrun[h]);
        float pv2 = __builtin_amdgcn_exp2f(sT[h][mt][2] - mrun[h]);
        float pv3 = __builtin_amdgcn_exp2f(sT[h][mt][3] - mrun[h]);
        fp16x2 p01 = __builtin_amdgcn_cvt_pkrtz(pv0, pv1);
        fp16x2 p23 = __builtin_amdgcn_cvt_pkrtz(pv2, pv3);
        half4_t pf;
        pf[0] = (_Float16)p01[0]; pf[1] = (_Float16)p01[1];
        pf[2] = (_Float16)p23[0]; pf[3] = (_Float16)p23[1];
        accl[h] = __builtin_amdgcn_mfma_f32_16x16x16f16(ones4, pf, accl[h], 0, 0, 0);
#pragma unroll
        for (int dt = 0; dt < 4; ++dt)
          acc[h][dt] = __builtin_amdgcn_mfma_f32_16x16x16f16(vf[dt][mt], pf,
                                                             acc[h][dt], 0, 0, 0);
      }
    }
    __builtin_amdgcn_s_setprio(0);

    __syncthreads();
  }

#pragma unroll
  for (int h = 0; h < 2; ++h) {
    float linv = 1.f / accl[h][0];
#pragma unroll
    for (int mt = 0; mt < 4; ++mt)
#pragma unroll
      for (int r = 0; r < 4; ++r)
        Osh[(32 * w + 16 * h + c) * LDO + 16 * mt + 4 * g + r] = acc[h][mt][r] * linv;
  }
  __syncthreads();
  {
    int f8 = t & 7;
#pragma unroll
    for (int i = 0; i < 4; ++i) {
      int q = (t >> 3) + 32 * i;
#pragma unroll
      for (int j = 0; j < 2; ++j) {
        int c4 = f8 + 8 * j;
        f32x4 o = *(f32x4*)(Osh + q * LDO + c4 * 4);
        *(float4*)(Ob + (size_t)(qb + q) * D_DIM + c4 * 4) =
            make_float4(o.x, o.y, o.z, o.w);
      }
    }
  }
}

extern "C" void kernel_launch(void* const* d_in, const int* in_sizes, int n_in,
                              void* d_out, int out_size, void* d_ws, size_t ws_size,
                              hipStream_t stream) {
  (void)in_sizes; (void)n_in; (void)out_size;
  const float* Q = (const float*)d_in[0];
  const float* K = (const float*)d_in[1];
  const float* V = (const float*)d_in[2];
  const int*   M = (const int*)d_in[3];
  float* O = (float*)d_out;

  if (ws_size >= WS_NEED && d_ws != nullptr) {
    _Float16* wsK = (_Float16*)d_ws;
    _Float16* wsV = wsK + (size_t)32 * S_LEN * D_DIM;               // +8MB
    _Float16* wsKeep = (_Float16*)((char*)d_ws + 16 * 1024 * 1024); // +16MB
    prep_kernel<<<dim3(2052), dim3(256), 0, stream>>>(K, V, M, wsK, wsV, wsKeep);
    // grid 1024: bh fast (XCD L2 locality), 32 q-tiles of 64 rows slow
    fattn_dma<<<dim3(32 * 32), dim3(256), 0, stream>>>(Q, wsK, wsV, wsKeep, O);
  } else {
    fattn_fb<<<dim3(32 * 16), dim3(256), 0, stream>>>(Q, K, V, M, O);
  }
}

// Round 10
// 151.972 us; speedup vs baseline: 1.0264x; 1.0264x over previous
//
#include <hip/hip_runtime.h>

typedef _Float16 half8_t __attribute__((ext_vector_type(8)));
typedef _Float16 half4_t __attribute__((ext_vector_type(4)));
typedef _Float16 half2_t __attribute__((ext_vector_type(2)));
typedef __fp16 fp16x2 __attribute__((ext_vector_type(2)));
typedef float f32x4 __attribute__((ext_vector_type(4)));

#define S_LEN 2048
#define D_DIM 64
#define SD (S_LEN * D_DIM)
#define LDK 72             // fallback kernel: f16 row stride
#define LDO 68             // f32 row stride for epilogue
#define THR 4.0f           // lazy-max threshold: stale-path P <= 2^4
#define WS_NEED ((size_t)(16 * 1024 * 1024 + 16384))

// ============================================================================
// PREP (once; proven): K -> swizzled f16 8KB tiles; V -> transposed,
// swizzled f16 8KB tiles with MASKED ROWS ZEROED; keep[] -> f16 {0,1}.
// K tile: byte(row,16B-gran j) = row*128 + ((16j) ^ ((row&7)<<4))
// V tile: byte(drow,8B-gran j2) = drow*128 + ((8j2) ^ ((drow&15)<<3))
// ============================================================================
__global__ __launch_bounds__(256)
void prep_kernel(const float* __restrict__ Kg, const float* __restrict__ Vg,
                 const int* __restrict__ Mg, _Float16* __restrict__ wsK,
                 _Float16* __restrict__ wsV, _Float16* __restrict__ wsKeep) {
  __shared__ float vt[64][68];
  const int blk = blockIdx.x;   // [0,1024) K; [1024,2048) V; [2048,2052) keep
  const int t = threadIdx.x;

  if (blk < 1024) {
    const int bh = blk >> 5, kt = blk & 31;
    const float* src = Kg + (size_t)bh * SD + (size_t)kt * 64 * D_DIM;
    char* dst = (char*)wsK + (size_t)blk * 8192;
#pragma unroll
    for (int i = 0; i < 2; ++i) {
      int task = t + 256 * i;        // 512 granules: row 0..63 x j 0..7
      int row = task >> 3, j = task & 7;
      float4 lo = *(const float4*)(src + row * D_DIM + 8 * j);
      float4 hi = *(const float4*)(src + row * D_DIM + 8 * j + 4);
      fp16x2 p0 = __builtin_amdgcn_cvt_pkrtz(lo.x, lo.y);
      fp16x2 p1 = __builtin_amdgcn_cvt_pkrtz(lo.z, lo.w);
      fp16x2 p2 = __builtin_amdgcn_cvt_pkrtz(hi.x, hi.y);
      fp16x2 p3 = __builtin_amdgcn_cvt_pkrtz(hi.z, hi.w);
      half8_t h;
      h[0] = (_Float16)p0[0]; h[1] = (_Float16)p0[1];
      h[2] = (_Float16)p1[0]; h[3] = (_Float16)p1[1];
      h[4] = (_Float16)p2[0]; h[5] = (_Float16)p2[1];
      h[6] = (_Float16)p3[0]; h[7] = (_Float16)p3[1];
      *(half8_t*)(dst + row * 128 + ((16 * j) ^ ((row & 7) << 4))) = h;
    }
  } else if (blk < 2048) {
    const int vb = blk - 1024;
    const int bh = vb >> 5, kt = vb & 31;
    const float* src = Vg + (size_t)bh * SD + (size_t)kt * 64 * D_DIM;
    const int* msk = Mg + (size_t)(bh >> 3) * S_LEN + kt * 64;
#pragma unroll
    for (int i = 0; i < 4; ++i) {
      int r = (t >> 4) + 16 * i, c4 = t & 15;
      *(float4*)&vt[r][c4 * 4] = *(const float4*)(src + r * D_DIM + c4 * 4);
    }
    __syncthreads();
    char* dst = (char*)wsV + (size_t)vb * 8192;
#pragma unroll
    for (int i = 0; i < 4; ++i) {
      int task = t + 256 * i;        // 1024 granules: drow 0..63 x j2 0..15
      int drow = task >> 4, j2 = task & 15, k0 = 4 * j2;
      int4 mv = *(const int4*)(msk + k0);
      float a  = vt[k0][drow]     * (float)mv.x;
      float b  = vt[k0 + 1][drow] * (float)mv.y;
      float cc = vt[k0 + 2][drow] * (float)mv.z;
      float d  = vt[k0 + 3][drow] * (float)mv.w;
      fp16x2 h0 = __builtin_amdgcn_cvt_pkrtz(a, b);
      fp16x2 h1 = __builtin_amdgcn_cvt_pkrtz(cc, d);
      half4_t h;
      h[0] = (_Float16)h0[0]; h[1] = (_Float16)h0[1];
      h[2] = (_Float16)h1[0]; h[3] = (_Float16)h1[1];
      *(half4_t*)(dst + drow * 128 + ((8 * j2) ^ ((drow & 15) << 3))) = h;
    }
  } else {
    const int b = blk - 2048;      // batch
    const int* src = Mg + (size_t)b * S_LEN + 8 * t;
    int4 m0 = *(const int4*)src;
    int4 m1 = *(const int4*)(src + 4);
    half8_t h;
    h[0] = (_Float16)(float)m0.x; h[1] = (_Float16)(float)m0.y;
    h[2] = (_Float16)(float)m0.z; h[3] = (_Float16)(float)m0.w;
    h[4] = (_Float16)(float)m1.x; h[5] = (_Float16)(float)m1.y;
    h[6] = (_Float16)(float)m1.z; h[7] = (_Float16)(float)m1.w;
    *(half8_t*)(wsKeep + (size_t)b * S_LEN + 8 * t) = h;
  }
}

// ============================================================================
// MAIN: R8 body + CLEAN T4 counted-vmcnt pipeline. R9's version was poisoned:
// the in-loop keep loads were GLOBAL (vmcnt ops), and in-order vmcnt forced
// an implicit vmcnt(0) drain before every PV — worse than R8. Now the 4
// staging global_load_lds are the ONLY vmem ops in the loop (keep vector is
// staged to LDS once; kA becomes a broadcast ds_read_b64 on lgkm).
// Triple-buffered K/V (3x16KB) + keep = 53248B LDS -> 3 blocks/CU.
// Per iter: vmcnt(4) [waits ONLY dma(kt); dma(kt+1) stays in flight] ->
// s_barrier [producer-wait-before-barrier => cross-wave visibility] ->
// issue dma(kt+2) [after barrier => 3-buffer overwrite is race-free] ->
// compute. vmcnt(0) only in the peeled last iteration.
// ============================================================================
__global__ __launch_bounds__(256, 3)
void fattn_dma(const float* __restrict__ Qg, const _Float16* __restrict__ wsK,
               const _Float16* __restrict__ wsV,
               const _Float16* __restrict__ wsKeep, float* __restrict__ Og) {
  __shared__ __align__(16) char smem[53248];
  // K bufs 3x8192 [0,24576); V bufs 3x8192 [24576,49152); keep [49152,53248)
  float* Osh = (float*)smem;            // epilogue reuse (17408B)
  char*  keepL = smem + 49152;

  const int t = threadIdx.x;
  const int w = t >> 6;
  const int lane = t & 63;
  const int g = lane >> 4;
  const int c = lane & 15;

  const int bh = blockIdx.x & 31;   // bh fast: ws pinned to one XCD's L2
  const int qt = blockIdx.x >> 5;
  const int qb = qt * 64;           // 64 q-rows per block, 16 per wave

  const float* Qb = Qg + (size_t)bh * SD;
  float*       Ob = Og + (size_t)bh * SD;
  const _Float16* keepB = wsKeep + (size_t)(bh >> 3) * S_LEN;  // H = 8

  // ---- Q^T B-frags for q = qb + 16w + c; fold 1/8 * log2(e) ----
  const float qscale = 0.125f * 1.44269504088896340736f;
  half8_t qf[2];
  {
    const float* qp = Qb + (size_t)(qb + 16 * w + c) * D_DIM + 8 * g;
#pragma unroll
    for (int ks = 0; ks < 2; ++ks) {
      float4 lo = *(const float4*)(qp + 32 * ks);
      float4 hi = *(const float4*)(qp + 32 * ks + 4);
      fp16x2 p0 = __builtin_amdgcn_cvt_pkrtz(lo.x * qscale, lo.y * qscale);
      fp16x2 p1 = __builtin_amdgcn_cvt_pkrtz(lo.z * qscale, lo.w * qscale);
      fp16x2 p2 = __builtin_amdgcn_cvt_pkrtz(hi.x * qscale, hi.y * qscale);
      fp16x2 p3 = __builtin_amdgcn_cvt_pkrtz(hi.z * qscale, hi.w * qscale);
      half8_t hh;
      hh[0] = (_Float16)p0[0]; hh[1] = (_Float16)p0[1];
      hh[2] = (_Float16)p1[0]; hh[3] = (_Float16)p1[1];
      hh[4] = (_Float16)p2[0]; hh[5] = (_Float16)p2[1];
      hh[6] = (_Float16)p3[0]; hh[7] = (_Float16)p3[1];
      qf[ks] = hh;
    }
  }

  // ---- DMA staging: per wave 2KB K + 2KB V (exactly 4 x 16B/lane issues) ----
  const size_t tbase = (size_t)bh * 262144;
  auto dma = [&](int buf, int kt) {
    const char* gK = (const char*)wsK + tbase + (size_t)kt * 8192 +
                     w * 2048 + lane * 16;
    const char* gV = (const char*)wsV + tbase + (size_t)kt * 8192 +
                     w * 2048 + lane * 16;
    char* lK = smem + 8192 * buf + w * 2048;
    char* lV = smem + 24576 + 8192 * buf + w * 2048;
    __builtin_amdgcn_global_load_lds((const float*)gK, (float*)lK, 16, 0, 0);
    __builtin_amdgcn_global_load_lds((const float*)(gK + 1024),
                                     (float*)(lK + 1024), 16, 0, 0);
    __builtin_amdgcn_global_load_lds((const float*)gV, (float*)lV, 16, 0, 0);
    __builtin_amdgcn_global_load_lds((const float*)(gV + 1024),
                                     (float*)(lV + 1024), 16, 0, 0);
  };

  f32x4 acc[4];
  f32x4 accl;
#pragma unroll
  for (int j = 0; j < 4; ++j) {
    accl[j] = 0.f;
#pragma unroll
    for (int i = 0; i < 4; ++i) acc[i][j] = 0.f;
  }
  float mrun = -1e30f;

  const int kxor = (c & 7) << 4;
  const int vxor = c << 3;

  // ---- iteration body (all in-loop vmem is the dma; kA is LDS) ----
  auto body = [&](int kt) __attribute__((always_inline)) {
    const char* Kc = smem + 8192 * (kt % 3);
    const char* Vc = smem + 24576 + 8192 * (kt % 3);

    // keep A-frags: broadcast ds_read_b64 (lgkm — invisible to vmcnt)
    half4_t kA[4];
#pragma unroll
    for (int mt = 0; mt < 4; ++mt)
      kA[mt] = *(const half4_t*)(keepL + kt * 128 + 32 * mt + 8 * g);

    // ---- S^T = K . Q^T ----
    f32x4 sT[4];
    __builtin_amdgcn_s_setprio(1);
#pragma unroll
    for (int mt = 0; mt < 4; ++mt) {
      const char* Krow = Kc + (16 * mt + c) * 128;
      f32x4 z;
#pragma unroll
      for (int j = 0; j < 4; ++j) z[j] = 0.f;
#pragma unroll
      for (int ks = 0; ks < 2; ++ks) {
        half8_t kf = *(const half8_t*)(Krow + ((ks * 64 + g * 16) ^ kxor));
        z = __builtin_amdgcn_mfma_f32_16x16x32_f16(kf, qf[ks], z, 0, 0, 0);
      }
      sT[mt] = z;
    }
    __builtin_amdgcn_s_setprio(0);

    // ---- V A-frags (K=16 PV), issued before softmax to hide LDS latency ----
    half4_t vf[4][4];  // [d-tile][k-step]
#pragma unroll
    for (int dt = 0; dt < 4; ++dt)
#pragma unroll
      for (int mtk = 0; mtk < 4; ++mtk)
        vf[dt][mtk] = *(const half4_t*)(Vc + (16 * dt + c) * 128 +
                                        ((32 * mtk + 8 * g) ^ vxor));

    // ---- lazy raw-score max: no cross-lane in the common path ----
    float tl = -1e30f;
#pragma unroll
    for (int mt = 0; mt < 4; ++mt)
      tl = fmaxf(tl, fmaxf(fmaxf(sT[mt][0], sT[mt][1]),
                           fmaxf(sT[mt][2], sT[mt][3])));
    if (!__all(tl <= mrun + THR)) {
      // rare: exact row-max update + alpha rescale (wave-uniform branch)
      float tmax = fmaxf(tl, __shfl_xor(tl, 16));
      tmax = fmaxf(tmax, __shfl_xor(tmax, 32));
      float mnew = fmaxf(mrun, tmax);
      float alpha = __builtin_amdgcn_exp2f(mrun - mnew);
      mrun = mnew;
#pragma unroll
      for (int j = 0; j < 4; ++j) {
        accl[j] *= alpha;
#pragma unroll
        for (int i = 0; i < 4; ++i) acc[i][j] *= alpha;
      }
    }

    // ---- exp + in-register pack + PV; l-sum via keep-MFMA ----
    __builtin_amdgcn_s_setprio(1);
#pragma unroll
    for (int mt = 0; mt < 4; ++mt) {
      float pv0 = __builtin_amdgcn_exp2f(sT[mt][0] - mrun);
      float pv1 = __builtin_amdgcn_exp2f(sT[mt][1] - mrun);
      float pv2 = __builtin_amdgcn_exp2f(sT[mt][2] - mrun);
      float pv3 = __builtin_amdgcn_exp2f(sT[mt][3] - mrun);
      fp16x2 p01 = __builtin_amdgcn_cvt_pkrtz(pv0, pv1);
      fp16x2 p23 = __builtin_amdgcn_cvt_pkrtz(pv2, pv3);
      half4_t pf;
      pf[0] = (_Float16)p01[0]; pf[1] = (_Float16)p01[1];
      pf[2] = (_Float16)p23[0]; pf[3] = (_Float16)p23[1];
      accl = __builtin_amdgcn_mfma_f32_16x16x16f16(kA[mt], pf, accl, 0, 0, 0);
#pragma unroll
      for (int dt = 0; dt < 4; ++dt)
        acc[dt] = __builtin_amdgcn_mfma_f32_16x16x16f16(vf[dt][mt], pf,
                                                        acc[dt], 0, 0, 0);
    }
    __builtin_amdgcn_s_setprio(0);
  };

  // ---- prologue: keep -> LDS (1 vmem op) + tiles 0,1 in flight ----
  __builtin_amdgcn_global_load_lds((const float*)((const char*)keepB + t * 16),
                                   (float*)(keepL + t * 16), 16, 0, 0);
  dma(0, 0);
  dma(1, 1);

  // ---- main loop: vmcnt(4) waits only the oldest dma; keep absorbed at 0 ----
  for (int kt = 0; kt < 31; ++kt) {
    asm volatile("s_waitcnt vmcnt(4)" ::: "memory");
    __builtin_amdgcn_s_barrier();           // dma(kt) + keep visible to all
    if (kt <= 29) dma((kt + 2) % 3, kt + 2);  // safe: all waves past iter kt-1
    body(kt);
  }
  // peeled last iteration: drain everything
  asm volatile("s_waitcnt vmcnt(0)" ::: "memory");
  __builtin_amdgcn_s_barrier();
  body(31);

  // ---- epilogue: /l, transpose O^T -> O via LDS, coalesced stores ----
  __syncthreads();   // all waves done reading K/V bufs (Osh overlays them)
  {
    float linv = 1.f / accl[0];   // keep-MFMA replicates l over rows
#pragma unroll
    for (int mt = 0; mt < 4; ++mt)
#pragma unroll
      for (int r = 0; r < 4; ++r)
        Osh[(16 * w + c) * LDO + 16 * mt + 4 * g + r] = acc[mt][r] * linv;
  }
  __syncthreads();
  {
    int f8 = t & 7;
#pragma unroll
    for (int i = 0; i < 2; ++i) {
      int q = (t >> 3) + 32 * i;
#pragma unroll
      for (int j = 0; j < 2; ++j) {
        int c4 = f8 + 8 * j;
        f32x4 o = *(f32x4*)(Osh + q * LDO + c4 * 4);
        *(float4*)(Ob + (size_t)(qb + q) * D_DIM + c4 * 4) =
            make_float4(o.x, o.y, o.z, o.w);
      }
    }
  }
}

// ============================================================================
// FALLBACK (round-3 kernel) — used only if ws_size < WS_NEED.
// ============================================================================
__global__ __launch_bounds__(256, 2)
void fattn_fb(const float* __restrict__ Qg, const float* __restrict__ Kg,
              const float* __restrict__ Vg, const int* __restrict__ Mg,
              float* __restrict__ Og) {
  __shared__ __align__(16) char smem[45056];
  float* Msh = (float*)(smem + 36864);
  float* Osh = (float*)smem;

  const int t = threadIdx.x;
  const int w = t >> 6;
  const int lane = t & 63;
  const int g = lane >> 4;
  const int c = lane & 15;

  const int bh = blockIdx.x & 31;
  const int qt = blockIdx.x >> 5;
  const int qb = qt * 128;

  const float* Qb = Qg + (size_t)bh * SD;
  const float* Kb = Kg + (size_t)bh * SD;
  const float* Vb = Vg + (size_t)bh * SD;
  const int*   Mb = Mg + (size_t)(bh >> 3) * S_LEN;
  float*       Ob = Og + (size_t)bh * SD;

  {
    int4 m0 = *(const int4*)(Mb + 8 * t);
    int4 m1 = *(const int4*)(Mb + 8 * t + 4);
    float4 f0, f1;
    f0.x = (float)(m0.x - 1) * 1e30f; f0.y = (float)(m0.y - 1) * 1e30f;
    f0.z = (float)(m0.z - 1) * 1e30f; f0.w = (float)(m0.w - 1) * 1e30f;
    f1.x = (float)(m1.x - 1) * 1e30f; f1.y = (float)(m1.y - 1) * 1e30f;
    f1.z = (float)(m1.z - 1) * 1e30f; f1.w = (float)(m1.w - 1) * 1e30f;
    *(float4*)(Msh + 8 * t) = f0;
    *(float4*)(Msh + 8 * t + 4) = f1;
  }

  const float qscale = 0.125f * 1.44269504088896340736f;
  half8_t qf[2][2];
#pragma unroll
  for (int h = 0; h < 2; ++h) {
    const float* qp = Qb + (size_t)(qb + 32 * w + 16 * h + c) * D_DIM + 8 * g;
#pragma unroll
    for (int ks = 0; ks < 2; ++ks) {
      float4 lo = *(const float4*)(qp + 32 * ks);
      float4 hi = *(const float4*)(qp + 32 * ks + 4);
      fp16x2 p0 = __builtin_amdgcn_cvt_pkrtz(lo.x * qscale, lo.y * qscale);
      fp16x2 p1 = __builtin_amdgcn_cvt_pkrtz(lo.z * qscale, lo.w * qscale);
      fp16x2 p2 = __builtin_amdgcn_cvt_pkrtz(hi.x * qscale, hi.y * qscale);
      fp16x2 p3 = __builtin_amdgcn_cvt_pkrtz(hi.z * qscale, hi.w * qscale);
      half8_t hh;
      hh[0] = (_Float16)p0[0]; hh[1] = (_Float16)p0[1];
      hh[2] = (_Float16)p1[0]; hh[3] = (_Float16)p1[1];
      hh[4] = (_Float16)p2[0]; hh[5] = (_Float16)p2[1];
      hh[6] = (_Float16)p3[0]; hh[7] = (_Float16)p3[1];
      qf[h][ks] = hh;
    }
  }

  const int krow0 = t >> 4;
  const int kc4   = t & 15;
  const int vp    = t >> 3;
  const int vkpl  = t & 7;

  float4 kr[4];
  float2 vr[8];
  auto prefetch = [&](int kb2) {
#pragma unroll
    for (int it = 0; it < 4; ++it)
      kr[it] = *(const float4*)(Kb + (size_t)(kb2 + krow0 + 16 * it) * D_DIM + kc4 * 4);
#pragma unroll
    for (int kc = 0; kc < 4; ++kc) {
      const float* vpp = Vb + (size_t)(kb2 + 2 * (vkpl + 8 * kc)) * D_DIM + 2 * vp;
      vr[2 * kc]     = *(const float2*)(vpp);
      vr[2 * kc + 1] = *(const float2*)(vpp + D_DIM);
    }
  };
  auto stage = [&](int buf) {
    _Float16* Kd = (_Float16*)(smem + 9216 * buf);
    _Float16* Vd = (_Float16*)(smem + 18432 + 9216 * buf);
#pragma unroll
    for (int it = 0; it < 4; ++it) {
      fp16x2 a  = __builtin_amdgcn_cvt_pkrtz(kr[it].x, kr[it].y);
      fp16x2 b2 = __builtin_amdgcn_cvt_pkrtz(kr[it].z, kr[it].w);
      half4_t h;
      h[0] = (_Float16)a[0]; h[1] = (_Float16)a[1];
      h[2] = (_Float16)b2[0]; h[3] = (_Float16)b2[1];
      *(half4_t*)(Kd + (krow0 + 16 * it) * LDK + kc4 * 4) = h;
    }
#pragma unroll
    for (int kc = 0; kc < 4; ++kc) {
      int kp = vkpl + 8 * kc;
      fp16x2 h0 = __builtin_amdgcn_cvt_pkrtz(vr[2 * kc].x, vr[2 * kc + 1].x);
      fp16x2 h1 = __builtin_amdgcn_cvt_pkrtz(vr[2 * kc].y, vr[2 * kc + 1].y);
      half2_t g0; g0[0] = (_Float16)h0[0]; g0[1] = (_Float16)h0[1];
      half2_t g1; g1[0] = (_Float16)h1[0]; g1[1] = (_Float16)h1[1];
      *(half2_t*)(Vd + (2 * vp) * LDK + 2 * kp) = g0;
      *(half2_t*)(Vd + (2 * vp + 1) * LDK + 2 * kp) = g1;
    }
  };

  f32x4 acc[2][4];
  f32x4 accl[2];
#pragma unroll
  for (int h = 0; h < 2; ++h) {
#pragma unroll
    for (int j = 0; j < 4; ++j) accl[h][j] = 0.f;
#pragma unroll
    for (int i = 0; i < 4; ++i)
#pragma unroll
      for (int j = 0; j < 4; ++j) acc[h][i][j] = 0.f;
  }
  float mrun[2] = {-1e30f, -1e30f};

  half4_t ones4;
  ones4[0] = (_Float16)1.0f; ones4[1] = (_Float16)1.0f;
  ones4[2] = (_Float16)1.0f; ones4[3] = (_Float16)1.0f;

  prefetch(0);
  stage(0);
  prefetch(64);
  __syncthreads();

  for (int kt = 0; kt < 32; ++kt) {
    const int kb = kt * 64;
    const int cur = kt & 1;

    if (kt < 31) stage(cur ^ 1);
    if (kt < 30) prefetch(kb + 128);

    const _Float16* Kc = (const _Float16*)(smem + 9216 * cur);
    const _Float16* Vc = (const _Float16*)(smem + 18432 + 9216 * cur);

    f32x4 sT[2][4];
    __builtin_amdgcn_s_setprio(1);
#pragma unroll
    for (int mt = 0; mt < 4; ++mt) {
      f32x4 z0, z1;
#pragma unroll
      for (int j = 0; j < 4; ++j) { z0[j] = 0.f; z1[j] = 0.f; }
#pragma unroll
      for (int ks = 0; ks < 2; ++ks) {
        half8_t kf = *(half8_t*)(Kc + (16 * mt + c) * LDK + ks * 32 + 8 * g);
        z0 = __builtin_amdgcn_mfma_f32_16x16x32_f16(kf, qf[0][ks], z0, 0, 0, 0);
        z1 = __builtin_amdgcn_mfma_f32_16x16x32_f16(kf, qf[1][ks], z1, 0, 0, 0);
      }
      sT[0][mt] = z0;
      sT[1][mt] = z1;
    }
    __builtin_amdgcn_s_setprio(0);

    half4_t vf[4][4];
#pragma unroll
    for (int dt = 0; dt < 4; ++dt)
#pragma unroll
      for (int kst = 0; kst < 4; ++kst)
        vf[dt][kst] = *(half4_t*)(Vc + (16 * dt + c) * LDK + 16 * kst + 4 * g);

    f32x4 mvf[4];
#pragma unroll
    for (int mt = 0; mt < 4; ++mt)
      mvf[mt] = *(const f32x4*)(Msh + kb + 16 * mt + 4 * g);
#pragma unroll
    for (int h = 0; h < 2; ++h)
#pragma unroll
      for (int mt = 0; mt < 4; ++mt)
#pragma unroll
        for (int r = 0; r < 4; ++r) sT[h][mt][r] += mvf[mt][r];

    float tl[2];
#pragma unroll
    for (int h = 0; h < 2; ++h) {
      float tm0 = fmaxf(fmaxf(sT[h][0][0], sT[h][0][1]),
                        fmaxf(sT[h][0][2], sT[h][0][3]));
      float tm1 = fmaxf(fmaxf(sT[h][1][0], sT[h][1][1]),
                        fmaxf(sT[h][1][2], sT[h][1][3]));
      float tm2 = fmaxf(fmaxf(sT[h][2][0], sT[h][2][1]),
                        fmaxf(sT[h][2][2], sT[h][2][3]));
      float tm3 = fmaxf(fmaxf(sT[h][3][0], sT[h][3][1]),
                        fmaxf(sT[h][3][2], sT[h][3][3]));
      tl[h] = fmaxf(fmaxf(tm0, tm1), fmaxf(tm2, tm3));
    }
    int ok0 = __all(tl[0] <= mrun[0] + THR);
    int ok1 = __all(tl[1] <= mrun[1] + THR);
    if (!(ok0 & ok1)) {
#pragma unroll
      for (int h = 0; h < 2; ++h) {
        float tmax = tl[h];
        tmax = fmaxf(tmax, __shfl_xor(tmax, 16));
        tmax = fmaxf(tmax, __shfl_xor(tmax, 32));
        float mnew = fmaxf(mrun[h], tmax);
        float alpha = __builtin_amdgcn_exp2f(mrun[h] - mnew);
        mrun[h] = mnew;
        accl[h][0] *= alpha; accl[h][1] *= alpha;
        accl[h][2] *= alpha; accl[h][3] *= alpha;
#pragma unroll
        for (int mt = 0; mt < 4; ++mt) {
          acc[h][mt][0] *= alpha; acc[h][mt][1] *= alpha;
          acc[h][mt][2] *= alpha; acc[h][mt][3] *= alpha;
        }
      }
    }

    __builtin_amdgcn_s_setprio(1);
#pragma unroll
    for (int h = 0; h < 2; ++h) {
#pragma unroll
      for (int mt = 0; mt < 4; ++mt) {
        float pv0 = __builtin_amdgcn_exp2f(sT[h][mt][0] - mrun[h]);
        float pv1 = __builtin_amdgcn_exp2f(sT[h][mt][1] - mrun[h]);
        float pv2 = __builtin_amdgcn_exp2f(sT[h][mt][2] - mrun[h]);
        float pv3 = __builtin_amdgcn_exp2f(sT[h][mt][3] - mrun[h]);
        fp16x2 p01 = __builtin_amdgcn_cvt_pkrtz(pv0, pv1);
        fp16x2 p23 = __builtin_amdgcn_cvt_pkrtz(pv2, pv3);
        half4_t pf;
        pf[0] = (_Float16)p01[0]; pf[1] = (_Float16)p01[1];
        pf[2] = (_Float16)p23[0]; pf[3] = (_Float16)p23[1];
        accl[h] = __builtin_amdgcn_mfma_f32_16x16x16f16(ones4, pf, accl[h], 0, 0, 0);
#pragma unroll
        for (int dt = 0; dt < 4; ++dt)
          acc[h][dt] = __builtin_amdgcn_mfma_f32_16x16x16f16(vf[dt][mt], pf,
                                                             acc[h][dt], 0, 0, 0);
      }
    }
    __builtin_amdgcn_s_setprio(0);

    __syncthreads();
  }

#pragma unroll
  for (int h = 0; h < 2; ++h) {
    float linv = 1.f / accl[h][0];
#pragma unroll
    for (int mt = 0; mt < 4; ++mt)
#pragma unroll
      for (int r = 0; r < 4; ++r)
        Osh[(32 * w + 16 * h + c) * LDO + 16 * mt + 4 * g + r] = acc[h][mt][r] * linv;
  }
  __syncthreads();
  {
    int f8 = t & 7;
#pragma unroll
    for (int i = 0; i < 4; ++i) {
      int q = (t >> 3) + 32 * i;
#pragma unroll
      for (int j = 0; j < 2; ++j) {
        int c4 = f8 + 8 * j;
        f32x4 o = *(f32x4*)(Osh + q * LDO + c4 * 4);
        *(float4*)(Ob + (size_t)(qb + q) * D_DIM + c4 * 4) =
            make_float4(o.x, o.y, o.z, o.w);
      }
    }
  }
}

extern "C" void kernel_launch(void* const* d_in, const int* in_sizes, int n_in,
                              void* d_out, int out_size, void* d_ws, size_t ws_size,
                              hipStream_t stream) {
  (void)in_sizes; (void)n_in; (void)out_size;
  const float* Q = (const float*)d_in[0];
  const float* K = (const float*)d_in[1];
  const float* V = (const float*)d_in[2];
  const int*   M = (const int*)d_in[3];
  float* O = (float*)d_out;

  if (ws_size >= WS_NEED && d_ws != nullptr) {
    _Float16* wsK = (_Float16*)d_ws;
    _Float16* wsV = wsK + (size_t)32 * S_LEN * D_DIM;               // +8MB
    _Float16* wsKeep = (_Float16*)((char*)d_ws + 16 * 1024 * 1024); // +16MB
    prep_kernel<<<dim3(2052), dim3(256), 0, stream>>>(K, V, M, wsK, wsV, wsKeep);
    // grid 1024: bh fast (XCD L2 locality), 32 q-tiles of 64 rows slow
    fattn_dma<<<dim3(32 * 32), dim3(256), 0, stream>>>(Q, wsK, wsV, wsKeep, O);
  } else {
    fattn_fb<<<dim3(32 * 16), dim3(256), 0, stream>>>(Q, K, V, M, O);
  }
}

// Round 11
// 142.161 us; speedup vs baseline: 1.0972x; 1.0690x over previous
//
#include <hip/hip_runtime.h>

typedef _Float16 half8_t __attribute__((ext_vector_type(8)));
typedef _Float16 half4_t __attribute__((ext_vector_type(4)));
typedef _Float16 half2_t __attribute__((ext_vector_type(2)));
typedef __fp16 fp16x2 __attribute__((ext_vector_type(2)));
typedef float f32x4 __attribute__((ext_vector_type(4)));

#define S_LEN 2048
#define D_DIM 64
#define SD (S_LEN * D_DIM)
#define BC 64
#define NKT (S_LEN / BC)   // 32 key tiles
#define LDK 72             // fallback kernel: f16 row stride (64 + 8 pad)
#define LDO 68             // f32 row stride for epilogue
#define THR 4.0f           // lazy-max threshold: stale-path P <= 2^4
#define WS_NEED ((size_t)16 * 1024 * 1024)

// ============================================================================
// BEST-MEASURED CONFIGURATION (round-5 bench: main 61.4us, harness 141.9us).
// 10 structural variants since (BC=128, 4 convoys/CU, counted-vmcnt x2,
// free-running register reads) all measured 63-255us. Reverted verbatim.
//
// PREP: K -> f16 tiles, V -> transposed f16 tiles, laid out in d_ws in the
// EXACT byte order the main kernel's LDS wants (XOR bank-swizzle baked in).
// K tile (8KB): byte(row,16B-granule j) = row*128 + ((16j) ^ ((row&7)<<4))
// V tile (8KB): byte(drow,8B-granule j2) = drow*128 + ((8j2) ^ ((drow&15)<<3))
// All 16 q-tile blocks of one bh previously re-did this conversion+staging
// (16x redundant); now it's done once and main stages via global_load_lds DMA.
// ============================================================================
__global__ __launch_bounds__(256)
void prep_kernel(const float* __restrict__ Kg, const float* __restrict__ Vg,
                 _Float16* __restrict__ wsK, _Float16* __restrict__ wsV) {
  __shared__ float vt[64][68];
  const int blk = blockIdx.x;   // [0,1024): K tiles; [1024,2048): V tiles
  const int t = threadIdx.x;

  if (blk < 1024) {
    const int bh = blk >> 5, kt = blk & 31;
    const float* src = Kg + (size_t)bh * SD + (size_t)kt * BC * D_DIM;
    char* dst = (char*)wsK + (size_t)blk * 8192;
#pragma unroll
    for (int i = 0; i < 2; ++i) {
      int task = t + 256 * i;        // 512 granules: row 0..63 x j 0..7
      int row = task >> 3, j = task & 7;
      float4 lo = *(const float4*)(src + row * D_DIM + 8 * j);
      float4 hi = *(const float4*)(src + row * D_DIM + 8 * j + 4);
      fp16x2 p0 = __builtin_amdgcn_cvt_pkrtz(lo.x, lo.y);
      fp16x2 p1 = __builtin_amdgcn_cvt_pkrtz(lo.z, lo.w);
      fp16x2 p2 = __builtin_amdgcn_cvt_pkrtz(hi.x, hi.y);
      fp16x2 p3 = __builtin_amdgcn_cvt_pkrtz(hi.z, hi.w);
      half8_t h;
      h[0] = (_Float16)p0[0]; h[1] = (_Float16)p0[1];
      h[2] = (_Float16)p1[0]; h[3] = (_Float16)p1[1];
      h[4] = (_Float16)p2[0]; h[5] = (_Float16)p2[1];
      h[6] = (_Float16)p3[0]; h[7] = (_Float16)p3[1];
      *(half8_t*)(dst + row * 128 + ((16 * j) ^ ((row & 7) << 4))) = h;
    }
  } else {
    const int vb = blk - 1024;
    const int bh = vb >> 5, kt = vb & 31;
    const float* src = Vg + (size_t)bh * SD + (size_t)kt * BC * D_DIM;
    // coalesced load of the 64x64 f32 V tile
#pragma unroll
    for (int i = 0; i < 4; ++i) {
      int r = (t >> 4) + 16 * i, c4 = t & 15;
      *(float4*)&vt[r][c4 * 4] = *(const float4*)(src + r * D_DIM + c4 * 4);
    }
    __syncthreads();
    char* dst = (char*)wsV + (size_t)vb * 8192;
#pragma unroll
    for (int i = 0; i < 4; ++i) {
      int task = t + 256 * i;        // 1024 granules: drow 0..63 x j2 0..15
      int drow = task >> 4, j2 = task & 15, k0 = 4 * j2;
      float a = vt[k0][drow], b = vt[k0 + 1][drow];
      float cc = vt[k0 + 2][drow], d = vt[k0 + 3][drow];
      fp16x2 h0 = __builtin_amdgcn_cvt_pkrtz(a, b);
      fp16x2 h1 = __builtin_amdgcn_cvt_pkrtz(cc, d);
      half4_t h;
      h[0] = (_Float16)h0[0]; h[1] = (_Float16)h0[1];
      h[2] = (_Float16)h1[0]; h[3] = (_Float16)h1[1];
      *(half4_t*)(dst + drow * 128 + ((8 * j2) ^ ((drow & 15) << 3))) = h;
    }
  }
}

// ============================================================================
// MAIN: lazy max, ones-MFMA l-sum, in-register P->PV (QK out == PV B-frag),
// K/V frags shared by 2 q-groups, with staging as pure DMA:
// 4 global_load_lds(16B) per wave per iter from the pre-converted, pre-swizzled
// f16 workspace. Zero staging VALU, zero ds_writes, zero prefetch registers.
// ============================================================================
__global__ __launch_bounds__(256, 2)
void fattn_dma(const float* __restrict__ Qg, const _Float16* __restrict__ wsK,
               const _Float16* __restrict__ wsV, const int* __restrict__ Mg,
               float* __restrict__ Og) {
  __shared__ __align__(16) char smem[40960];
  // K dbuf 2x8192 [0,16384); V dbuf 2x8192 [16384,32768); mask [32768,40960)
  float* Msh = (float*)(smem + 32768);
  float* Osh = (float*)smem;   // epilogue reuse (34816B, mask dead by then)

  const int t = threadIdx.x;
  const int w = t >> 6;
  const int lane = t & 63;
  const int g = lane >> 4;
  const int c = lane & 15;

  const int bh = blockIdx.x & 31;
  const int qt = blockIdx.x >> 5;
  const int qb = qt * 128;

  const float* Qb = Qg + (size_t)bh * SD;
  const int*   Mb = Mg + (size_t)(bh >> 3) * S_LEN;  // H = 8
  float*       Ob = Og + (size_t)bh * SD;

  // ---- stage additive mask -> LDS once ----
  {
    int4 m0 = *(const int4*)(Mb + 8 * t);
    int4 m1 = *(const int4*)(Mb + 8 * t + 4);
    float4 f0, f1;
    f0.x = (float)(m0.x - 1) * 1e30f; f0.y = (float)(m0.y - 1) * 1e30f;
    f0.z = (float)(m0.z - 1) * 1e30f; f0.w = (float)(m0.w - 1) * 1e30f;
    f1.x = (float)(m1.x - 1) * 1e30f; f1.y = (float)(m1.y - 1) * 1e30f;
    f1.z = (float)(m1.z - 1) * 1e30f; f1.w = (float)(m1.w - 1) * 1e30f;
    *(float4*)(Msh + 8 * t) = f0;
    *(float4*)(Msh + 8 * t + 4) = f1;
  }

  // ---- Q^T B-frags; fold 1/8 * log2(e) ----
  const float qscale = 0.125f * 1.44269504088896340736f;
  half8_t qf[2][2];
#pragma unroll
  for (int h = 0; h < 2; ++h) {
    const float* qp = Qb + (size_t)(qb + 32 * w + 16 * h + c) * D_DIM + 8 * g;
#pragma unroll
    for (int ks = 0; ks < 2; ++ks) {
      float4 lo = *(const float4*)(qp + 32 * ks);
      float4 hi = *(const float4*)(qp + 32 * ks + 4);
      fp16x2 p0 = __builtin_amdgcn_cvt_pkrtz(lo.x * qscale, lo.y * qscale);
      fp16x2 p1 = __builtin_amdgcn_cvt_pkrtz(lo.z * qscale, lo.w * qscale);
      fp16x2 p2 = __builtin_amdgcn_cvt_pkrtz(hi.x * qscale, hi.y * qscale);
      fp16x2 p3 = __builtin_amdgcn_cvt_pkrtz(hi.z * qscale, hi.w * qscale);
      half8_t hh;
      hh[0] = (_Float16)p0[0]; hh[1] = (_Float16)p0[1];
      hh[2] = (_Float16)p1[0]; hh[3] = (_Float16)p1[1];
      hh[4] = (_Float16)p2[0]; hh[5] = (_Float16)p2[1];
      hh[6] = (_Float16)p3[0]; hh[7] = (_Float16)p3[1];
      qf[h][ks] = hh;
    }
  }

  // ---- DMA staging: per wave, 2KB of K + 2KB of V (4 x 16B/lane issues) ----
  const size_t tile_base0 = (size_t)bh * 32 * 8192;
  auto dma = [&](int buf, int kt) {
    const char* gK = (const char*)wsK + tile_base0 + (size_t)kt * 8192 +
                     w * 2048 + lane * 16;
    const char* gV = (const char*)wsV + tile_base0 + (size_t)kt * 8192 +
                     w * 2048 + lane * 16;
    char* lK = smem + 8192 * buf + w * 2048;
    char* lV = smem + 16384 + 8192 * buf + w * 2048;
    __builtin_amdgcn_global_load_lds((const float*)gK, (float*)lK, 16, 0, 0);
    __builtin_amdgcn_global_load_lds((const float*)(gK + 1024), (float*)(lK + 1024), 16, 0, 0);
    __builtin_amdgcn_global_load_lds((const float*)gV, (float*)lV, 16, 0, 0);
    __builtin_amdgcn_global_load_lds((const float*)(gV + 1024), (float*)(lV + 1024), 16, 0, 0);
  };

  f32x4 acc[2][4];
  f32x4 accl[2];
#pragma unroll
  for (int h = 0; h < 2; ++h) {
#pragma unroll
    for (int j = 0; j < 4; ++j) accl[h][j] = 0.f;
#pragma unroll
    for (int i = 0; i < 4; ++i)
#pragma unroll
      for (int j = 0; j < 4; ++j) acc[h][i][j] = 0.f;
  }
  float mrun[2] = {-1e30f, -1e30f};

  half4_t ones4;
  ones4[0] = (_Float16)1.0f; ones4[1] = (_Float16)1.0f;
  ones4[2] = (_Float16)1.0f; ones4[3] = (_Float16)1.0f;

  // loop-invariant swizzled frag byte-offsets (per lane)
  const int kxor = (c & 7) << 4;
  const int vxor = c << 3;

  dma(0, 0);
  __syncthreads();   // drains vmcnt: tile 0 resident

  for (int kt = 0; kt < NKT; ++kt) {
    const int cur = kt & 1;
    if (kt < NKT - 1) dma(cur ^ 1, kt + 1);   // in flight under compute

    const char* Kc = smem + 8192 * cur;
    const char* Vc = smem + 16384 + 8192 * cur;

    // ---- S^T = K . Q^T for both q-groups; K frag read ONCE ----
    f32x4 sT[2][4];
    __builtin_amdgcn_s_setprio(1);
#pragma unroll
    for (int mt = 0; mt < 4; ++mt) {
      f32x4 z0, z1;
#pragma unroll
      for (int j = 0; j < 4; ++j) { z0[j] = 0.f; z1[j] = 0.f; }
#pragma unroll
      for (int ks = 0; ks < 2; ++ks) {
        half8_t kf = *(const half8_t*)(Kc + (16 * mt + c) * 128 +
                                       ((ks * 64 + g * 16) ^ kxor));
        z0 = __builtin_amdgcn_mfma_f32_16x16x32_f16(kf, qf[0][ks], z0, 0, 0, 0);
        z1 = __builtin_amdgcn_mfma_f32_16x16x32_f16(kf, qf[1][ks], z1, 0, 0, 0);
      }
      sT[0][mt] = z0;
      sT[1][mt] = z1;
    }
    __builtin_amdgcn_s_setprio(0);

    // ---- V A-frags (K=16 PV), shared by both groups ----
    half4_t vf[4][4];  // [d-tile][k-step]
#pragma unroll
    for (int dt = 0; dt < 4; ++dt)
#pragma unroll
      for (int mtk = 0; mtk < 4; ++mtk)
        vf[dt][mtk] = *(const half4_t*)(Vc + (16 * dt + c) * 128 +
                                        ((32 * mtk + 8 * g) ^ vxor));

    // ---- additive mask ----
    f32x4 mvf[4];
#pragma unroll
    for (int mt = 0; mt < 4; ++mt)
      mvf[mt] = *(const f32x4*)(Msh + kt * BC + 16 * mt + 4 * g);
#pragma unroll
    for (int h = 0; h < 2; ++h)
#pragma unroll
      for (int mt = 0; mt < 4; ++mt)
#pragma unroll
        for (int r = 0; r < 4; ++r) sT[h][mt][r] += mvf[mt][r];

    // ---- lazy max: per-lane local max only in the common path ----
    float tl[2];
#pragma unroll
    for (int h = 0; h < 2; ++h) {
      float tm0 = fmaxf(fmaxf(sT[h][0][0], sT[h][0][1]),
                        fmaxf(sT[h][0][2], sT[h][0][3]));
      float tm1 = fmaxf(fmaxf(sT[h][1][0], sT[h][1][1]),
                        fmaxf(sT[h][1][2], sT[h][1][3]));
      float tm2 = fmaxf(fmaxf(sT[h][2][0], sT[h][2][1]),
                        fmaxf(sT[h][2][2], sT[h][2][3]));
      float tm3 = fmaxf(fmaxf(sT[h][3][0], sT[h][3][1]),
                        fmaxf(sT[h][3][2], sT[h][3][3]));
      tl[h] = fmaxf(fmaxf(tm0, tm1), fmaxf(tm2, tm3));
    }
    int ok0 = __all(tl[0] <= mrun[0] + THR);
    int ok1 = __all(tl[1] <= mrun[1] + THR);
    if (!(ok0 & ok1)) {
#pragma unroll
      for (int h = 0; h < 2; ++h) {
        float tmax = tl[h];
        tmax = fmaxf(tmax, __shfl_xor(tmax, 16));
        tmax = fmaxf(tmax, __shfl_xor(tmax, 32));
        float mnew = fmaxf(mrun[h], tmax);
        float alpha = __builtin_amdgcn_exp2f(mrun[h] - mnew);
        mrun[h] = mnew;
        accl[h][0] *= alpha; accl[h][1] *= alpha;
        accl[h][2] *= alpha; accl[h][3] *= alpha;
#pragma unroll
        for (int mt = 0; mt < 4; ++mt) {
          acc[h][mt][0] *= alpha; acc[h][mt][1] *= alpha;
          acc[h][mt][2] *= alpha; acc[h][mt][3] *= alpha;
        }
      }
    }

    // ---- exp + in-register pack + PV; l-sum via ones-MFMA ----
    __builtin_amdgcn_s_setprio(1);
#pragma unroll
    for (int h = 0; h < 2; ++h) {
#pragma unroll
      for (int mt = 0; mt < 4; ++mt) {
        float pv0 = __builtin_amdgcn_exp2f(sT[h][mt][0] - mrun[h]);
        float pv1 = __builtin_amdgcn_exp2f(sT[h][mt][1] - mrun[h]);
        float pv2 = __builtin_amdgcn_exp2f(sT[h][mt][2] - mrun[h]);
        float pv3 = __builtin_amdgcn_exp2f(sT[h][mt][3] - mrun[h]);
        fp16x2 p01 = __builtin_amdgcn_cvt_pkrtz(pv0, pv1);
        fp16x2 p23 = __builtin_amdgcn_cvt_pkrtz(pv2, pv3);
        half4_t pf;
        pf[0] = (_Float16)p01[0]; pf[1] = (_Float16)p01[1];
        pf[2] = (_Float16)p23[0]; pf[3] = (_Float16)p23[1];
        accl[h] = __builtin_amdgcn_mfma_f32_16x16x16f16(ones4, pf, accl[h], 0, 0, 0);
#pragma unroll
        for (int dt = 0; dt < 4; ++dt)
          acc[h][dt] = __builtin_amdgcn_mfma_f32_16x16x16f16(vf[dt][mt], pf,
                                                             acc[h][dt], 0, 0, 0);
      }
    }
    __builtin_amdgcn_s_setprio(0);

    __syncthreads();  // drains vmcnt (DMA kt+1 done) + lgkm; guards swap
  }

  // ---- epilogue: /l, transpose O^T -> O via LDS, coalesced stores ----
#pragma unroll
  for (int h = 0; h < 2; ++h) {
    float linv = 1.f / accl[h][0];
#pragma unroll
    for (int mt = 0; mt < 4; ++mt)
#pragma unroll
      for (int r = 0; r < 4; ++r)
        Osh[(32 * w + 16 * h + c) * LDO + 16 * mt + 4 * g + r] = acc[h][mt][r] * linv;
  }
  __syncthreads();
  {
    int f8 = t & 7;
#pragma unroll
    for (int i = 0; i < 4; ++i) {
      int q = (t >> 3) + 32 * i;
#pragma unroll
      for (int j = 0; j < 2; ++j) {
        int c4 = f8 + 8 * j;
        f32x4 o = *(f32x4*)(Osh + q * LDO + c4 * 4);
        *(float4*)(Ob + (size_t)(qb + q) * D_DIM + c4 * 4) =
            make_float4(o.x, o.y, o.z, o.w);
      }
    }
  }
}

// ============================================================================
// FALLBACK (round-3 kernel, 87us) — used only if ws_size < 16MB.
// ============================================================================
__global__ __launch_bounds__(256, 2)
void fattn_fb(const float* __restrict__ Qg, const float* __restrict__ Kg,
              const float* __restrict__ Vg, const int* __restrict__ Mg,
              float* __restrict__ Og) {
  __shared__ __align__(16) char smem[45056];
  float* Msh = (float*)(smem + 36864);
  float* Osh = (float*)smem;

  const int t = threadIdx.x;
  const int w = t >> 6;
  const int lane = t & 63;
  const int g = lane >> 4;
  const int c = lane & 15;

  const int bh = blockIdx.x & 31;
  const int qt = blockIdx.x >> 5;
  const int qb = qt * 128;

  const float* Qb = Qg + (size_t)bh * SD;
  const float* Kb = Kg + (size_t)bh * SD;
  const float* Vb = Vg + (size_t)bh * SD;
  const int*   Mb = Mg + (size_t)(bh >> 3) * S_LEN;
  float*       Ob = Og + (size_t)bh * SD;

  {
    int4 m0 = *(const int4*)(Mb + 8 * t);
    int4 m1 = *(const int4*)(Mb + 8 * t + 4);
    float4 f0, f1;
    f0.x = (float)(m0.x - 1) * 1e30f; f0.y = (float)(m0.y - 1) * 1e30f;
    f0.z = (float)(m0.z - 1) * 1e30f; f0.w = (float)(m0.w - 1) * 1e30f;
    f1.x = (float)(m1.x - 1) * 1e30f; f1.y = (float)(m1.y - 1) * 1e30f;
    f1.z = (float)(m1.z - 1) * 1e30f; f1.w = (float)(m1.w - 1) * 1e30f;
    *(float4*)(Msh + 8 * t) = f0;
    *(float4*)(Msh + 8 * t + 4) = f1;
  }

  const float qscale = 0.125f * 1.44269504088896340736f;
  half8_t qf[2][2];
#pragma unroll
  for (int h = 0; h < 2; ++h) {
    const float* qp = Qb + (size_t)(qb + 32 * w + 16 * h + c) * D_DIM + 8 * g;
#pragma unroll
    for (int ks = 0; ks < 2; ++ks) {
      float4 lo = *(const float4*)(qp + 32 * ks);
      float4 hi = *(const float4*)(qp + 32 * ks + 4);
      fp16x2 p0 = __builtin_amdgcn_cvt_pkrtz(lo.x * qscale, lo.y * qscale);
      fp16x2 p1 = __builtin_amdgcn_cvt_pkrtz(lo.z * qscale, lo.w * qscale);
      fp16x2 p2 = __builtin_amdgcn_cvt_pkrtz(hi.x * qscale, hi.y * qscale);
      fp16x2 p3 = __builtin_amdgcn_cvt_pkrtz(hi.z * qscale, hi.w * qscale);
      half8_t hh;
      hh[0] = (_Float16)p0[0]; hh[1] = (_Float16)p0[1];
      hh[2] = (_Float16)p1[0]; hh[3] = (_Float16)p1[1];
      hh[4] = (_Float16)p2[0]; hh[5] = (_Float16)p2[1];
      hh[6] = (_Float16)p3[0]; hh[7] = (_Float16)p3[1];
      qf[h][ks] = hh;
    }
  }

  const int krow0 = t >> 4;
  const int kc4   = t & 15;
  const int vp    = t >> 3;
  const int vkpl  = t & 7;

  float4 kr[4];
  float2 vr[8];
  auto prefetch = [&](int kb2) {
#pragma unroll
    for (int it = 0; it < 4; ++it)
      kr[it] = *(const float4*)(Kb + (size_t)(kb2 + krow0 + 16 * it) * D_DIM + kc4 * 4);
#pragma unroll
    for (int kc = 0; kc < 4; ++kc) {
      const float* vpp = Vb + (size_t)(kb2 + 2 * (vkpl + 8 * kc)) * D_DIM + 2 * vp;
      vr[2 * kc]     = *(const float2*)(vpp);
      vr[2 * kc + 1] = *(const float2*)(vpp + D_DIM);
    }
  };
  auto stage = [&](int buf) {
    _Float16* Kd = (_Float16*)(smem + 9216 * buf);
    _Float16* Vd = (_Float16*)(smem + 18432 + 9216 * buf);
#pragma unroll
    for (int it = 0; it < 4; ++it) {
      fp16x2 a  = __builtin_amdgcn_cvt_pkrtz(kr[it].x, kr[it].y);
      fp16x2 b2 = __builtin_amdgcn_cvt_pkrtz(kr[it].z, kr[it].w);
      half4_t h;
      h[0] = (_Float16)a[0]; h[1] = (_Float16)a[1];
      h[2] = (_Float16)b2[0]; h[3] = (_Float16)b2[1];
      *(half4_t*)(Kd + (krow0 + 16 * it) * LDK + kc4 * 4) = h;
    }
#pragma unroll
    for (int kc = 0; kc < 4; ++kc) {
      int kp = vkpl + 8 * kc;
      fp16x2 h0 = __builtin_amdgcn_cvt_pkrtz(vr[2 * kc].x, vr[2 * kc + 1].x);
      fp16x2 h1 = __builtin_amdgcn_cvt_pkrtz(vr[2 * kc].y, vr[2 * kc + 1].y);
      half2_t g0; g0[0] = (_Float16)h0[0]; g0[1] = (_Float16)h0[1];
      half2_t g1; g1[0] = (_Float16)h1[0]; g1[1] = (_Float16)h1[1];
      *(half2_t*)(Vd + (2 * vp) * LDK + 2 * kp) = g0;
      *(half2_t*)(Vd + (2 * vp + 1) * LDK + 2 * kp) = g1;
    }
  };

  f32x4 acc[2][4];
  f32x4 accl[2];
#pragma unroll
  for (int h = 0; h < 2; ++h) {
#pragma unroll
    for (int j = 0; j < 4; ++j) accl[h][j] = 0.f;
#pragma unroll
    for (int i = 0; i < 4; ++i)
#pragma unroll
      for (int j = 0; j < 4; ++j) acc[h][i][j] = 0.f;
  }
  float mrun[2] = {-1e30f, -1e30f};

  half4_t ones4;
  ones4[0] = (_Float16)1.0f; ones4[1] = (_Float16)1.0f;
  ones4[2] = (_Float16)1.0f; ones4[3] = (_Float16)1.0f;

  prefetch(0);
  stage(0);
  prefetch(BC);
  __syncthreads();

  for (int kt = 0; kt < NKT; ++kt) {
    const int kb = kt * BC;
    const int cur = kt & 1;

    if (kt < NKT - 1) stage(cur ^ 1);
    if (kt < NKT - 2) prefetch(kb + 2 * BC);

    const _Float16* Kc = (const _Float16*)(smem + 9216 * cur);
    const _Float16* Vc = (const _Float16*)(smem + 18432 + 9216 * cur);

    f32x4 sT[2][4];
    __builtin_amdgcn_s_setprio(1);
#pragma unroll
    for (int mt = 0; mt < 4; ++mt) {
      f32x4 z0, z1;
#pragma unroll
      for (int j = 0; j < 4; ++j) { z0[j] = 0.f; z1[j] = 0.f; }
#pragma unroll
      for (int ks = 0; ks < 2; ++ks) {
        half8_t kf = *(half8_t*)(Kc + (16 * mt + c) * LDK + ks * 32 + 8 * g);
        z0 = __builtin_amdgcn_mfma_f32_16x16x32_f16(kf, qf[0][ks], z0, 0, 0, 0);
        z1 = __builtin_amdgcn_mfma_f32_16x16x32_f16(kf, qf[1][ks], z1, 0, 0, 0);
      }
      sT[0][mt] = z0;
      sT[1][mt] = z1;
    }
    __builtin_amdgcn_s_setprio(0);

    half4_t vf[4][4];
#pragma unroll
    for (int dt = 0; dt < 4; ++dt)
#pragma unroll
      for (int kst = 0; kst < 4; ++kst)
        vf[dt][kst] = *(half4_t*)(Vc + (16 * dt + c) * LDK + 16 * kst + 4 * g);

    f32x4 mvf[4];
#pragma unroll
    for (int mt = 0; mt < 4; ++mt)
      mvf[mt] = *(const f32x4*)(Msh + kb + 16 * mt + 4 * g);
#pragma unroll
    for (int h = 0; h < 2; ++h)
#pragma unroll
      for (int mt = 0; mt < 4; ++mt)
#pragma unroll
        for (int r = 0; r < 4; ++r) sT[h][mt][r] += mvf[mt][r];

    float tl[2];
#pragma unroll
    for (int h = 0; h < 2; ++h) {
      float tm0 = fmaxf(fmaxf(sT[h][0][0], sT[h][0][1]),
                        fmaxf(sT[h][0][2], sT[h][0][3]));
      float tm1 = fmaxf(fmaxf(sT[h][1][0], sT[h][1][1]),
                        fmaxf(sT[h][1][2], sT[h][1][3]));
      float tm2 = fmaxf(fmaxf(sT[h][2][0], sT[h][2][1]),
                        fmaxf(sT[h][2][2], sT[h][2][3]));
      float tm3 = fmaxf(fmaxf(sT[h][3][0], sT[h][3][1]),
                        fmaxf(sT[h][3][2], sT[h][3][3]));
      tl[h] = fmaxf(fmaxf(tm0, tm1), fmaxf(tm2, tm3));
    }
    int ok0 = __all(tl[0] <= mrun[0] + THR);
    int ok1 = __all(tl[1] <= mrun[1] + THR);
    if (!(ok0 & ok1)) {
#pragma unroll
      for (int h = 0; h < 2; ++h) {
        float tmax = tl[h];
        tmax = fmaxf(tmax, __shfl_xor(tmax, 16));
        tmax = fmaxf(tmax, __shfl_xor(tmax, 32));
        float mnew = fmaxf(mrun[h], tmax);
        float alpha = __builtin_amdgcn_exp2f(mrun[h] - mnew);
        mrun[h] = mnew;
        accl[h][0] *= alpha; accl[h][1] *= alpha;
        accl[h][2] *= alpha; accl[h][3] *= alpha;
#pragma unroll
        for (int mt = 0; mt < 4; ++mt) {
          acc[h][mt][0] *= alpha; acc[h][mt][1] *= alpha;
          acc[h][mt][2] *= alpha; acc[h][mt][3] *= alpha;
        }
      }
    }

    __builtin_amdgcn_s_setprio(1);
#pragma unroll
    for (int h = 0; h < 2; ++h) {
#pragma unroll
      for (int mt = 0; mt < 4; ++mt) {
        float pv0 = __builtin_amdgcn_exp2f(sT[h][mt][0] - mrun[h]);
        float pv1 = __builtin_amdgcn_exp2f(sT[h][mt][1] - mrun[h]);
        float pv2 = __builtin_amdgcn_exp2f(sT[h][mt][2] - mrun[h]);
        float pv3 = __builtin_amdgcn_exp2f(sT[h][mt][3] - mrun[h]);
        fp16x2 p01 = __builtin_amdgcn_cvt_pkrtz(pv0, pv1);
        fp16x2 p23 = __builtin_amdgcn_cvt_pkrtz(pv2, pv3);
        half4_t pf;
        pf[0] = (_Float16)p01[0]; pf[1] = (_Float16)p01[1];
        pf[2] = (_Float16)p23[0]; pf[3] = (_Float16)p23[1];
        accl[h] = __builtin_amdgcn_mfma_f32_16x16x16f16(ones4, pf, accl[h], 0, 0, 0);
#pragma unroll
        for (int dt = 0; dt < 4; ++dt)
          acc[h][dt] = __builtin_amdgcn_mfma_f32_16x16x16f16(vf[dt][mt], pf,
                                                             acc[h][dt], 0, 0, 0);
      }
    }
    __builtin_amdgcn_s_setprio(0);

    __syncthreads();
  }

#pragma unroll
  for (int h = 0; h < 2; ++h) {
    float linv = 1.f / accl[h][0];
#pragma unroll
    for (int mt = 0; mt < 4; ++mt)
#pragma unroll
      for (int r = 0; r < 4; ++r)
        Osh[(32 * w + 16 * h + c) * LDO + 16 * mt + 4 * g + r] = acc[h][mt][r] * linv;
  }
  __syncthreads();
  {
    int f8 = t & 7;
#pragma unroll
    for (int i = 0; i < 4; ++i) {
      int q = (t >> 3) + 32 * i;
#pragma unroll
      for (int j = 0; j < 2; ++j) {
        int c4 = f8 + 8 * j;
        f32x4 o = *(f32x4*)(Osh + q * LDO + c4 * 4);
        *(float4*)(Ob + (size_t)(qb + q) * D_DIM + c4 * 4) =
            make_float4(o.x, o.y, o.z, o.w);
      }
    }
  }
}

extern "C" void kernel_launch(void* const* d_in, const int* in_sizes, int n_in,
                              void* d_out, int out_size, void* d_ws, size_t ws_size,
                              hipStream_t stream) {
  (void)in_sizes; (void)n_in; (void)out_size;
  const float* Q = (const float*)d_in[0];
  const float* K = (const float*)d_in[1];
  const float* V = (const float*)d_in[2];
  const int*   M = (const int*)d_in[3];
  float* O = (float*)d_out;

  if (ws_size >= WS_NEED && d_ws != nullptr) {
    _Float16* wsK = (_Float16*)d_ws;
    _Float16* wsV = wsK + (size_t)32 * S_LEN * D_DIM;   // +8MB
    prep_kernel<<<dim3(2048), dim3(256), 0, stream>>>(K, V, wsK, wsV);
    fattn_dma<<<dim3(32 * 16), dim3(256), 0, stream>>>(Q, wsK, wsV, M, O);
  } else {
    fattn_fb<<<dim3(32 * 16), dim3(256), 0, stream>>>(Q, K, V, M, O);
  }
}

// Round 12
// 122.201 us; speedup vs baseline: 1.2764x; 1.1633x over previous
//
#include <hip/hip_runtime.h>

typedef _Float16 half8_t __attribute__((ext_vector_type(8)));
typedef _Float16 half4_t __attribute__((ext_vector_type(4)));
typedef _Float16 half2_t __attribute__((ext_vector_type(2)));
typedef __fp16 fp16x2 __attribute__((ext_vector_type(2)));
typedef float f32x4 __attribute__((ext_vector_type(4)));

#define S_LEN 2048
#define D_DIM 64
#define SD (S_LEN * D_DIM)
#define BC 64
#define LDK 72             // fallback kernel: f16 row stride (64 + 8 pad)
#define LDO 68             // f32 row stride for epilogue
#define THR 4.0f           // lazy-max threshold: stale-path P <= 2^4
// ws: wsK 8MB | wsV 8MB | idx 4x2048 ints (32KB) | L 4 ints
#define WS_NEED ((size_t)(16 * 1024 * 1024) + (size_t)4 * S_LEN * 4 + 64)

// ============================================================================
// KEY-COMPACTION STRATEGY (round 12). The key-padding mask keeps ~50% of
// keys, identically for all queries/heads of a batch; masked keys contribute
// EXACTLY 0 to the reference output (exp(s-1e30-max) underflows to 0.0f).
// Rounds 5-11 proved the main loop's time scales with iteration count and
// that no schedule variant beats the round-5 structure. So: compact the kept
// keys once in prep; the main kernel (round-5 body verbatim) runs
// NT=(L+63)/64 ~ 17 iterations instead of 32, with zero mask VALU.
// l-sum counts kept keys via ones-MFMA (full tiles) / keep-frag (tail tile).
// ============================================================================

// ---- per batch: prefix-sum compaction of the mask -> idx list + length ----
__global__ __launch_bounds__(256)
void compact_kernel(const int* __restrict__ Mg, int* __restrict__ idxp,
                    int* __restrict__ Lp) {
  __shared__ int pre[256];
  const int b = blockIdx.x;
  const int t = threadIdx.x;
  const int* m = Mg + (size_t)b * S_LEN + 8 * t;
  int4 m0 = *(const int4*)m;
  int4 m1 = *(const int4*)(m + 4);
  int v0 = m0.x, v1 = m0.y, v2 = m0.z, v3 = m0.w;
  int v4 = m1.x, v5 = m1.y, v6 = m1.z, v7 = m1.w;
  int c = v0 + v1 + v2 + v3 + v4 + v5 + v6 + v7;
  pre[t] = c;
  __syncthreads();
  for (int off = 1; off < 256; off <<= 1) {
    int x = (t >= off) ? pre[t - off] : 0;
    __syncthreads();
    pre[t] += x;
    __syncthreads();
  }
  int pos = pre[t] - c;   // exclusive prefix
  int* dst = idxp + (size_t)b * S_LEN;
  int base = 8 * t;
  if (v0) dst[pos++] = base + 0;
  if (v1) dst[pos++] = base + 1;
  if (v2) dst[pos++] = base + 2;
  if (v3) dst[pos++] = base + 3;
  if (v4) dst[pos++] = base + 4;
  if (v5) dst[pos++] = base + 5;
  if (v6) dst[pos++] = base + 6;
  if (v7) dst[pos++] = base + 7;
  if (t == 255) Lp[b] = pre[255];
}

// ---- gather-prep: compacted K -> swizzled f16 tiles; compacted V ->
//      transposed swizzled f16 tiles; tail rows (j >= L) zero-filled.
// K tile (8KB): byte(row,16B-granule j) = row*128 + ((16j) ^ ((row&7)<<4))
// V tile (8KB): byte(drow,8B-granule j2) = drow*128 + ((8j2) ^ ((drow&15)<<3))
__global__ __launch_bounds__(256)
void prep_kernel(const float* __restrict__ Kg, const float* __restrict__ Vg,
                 const int* __restrict__ idxp, const int* __restrict__ Lp,
                 _Float16* __restrict__ wsK, _Float16* __restrict__ wsV) {
  __shared__ float vt[64][68];
  __shared__ int ridx[64];
  const int blk = blockIdx.x;   // [0,1024): K tiles; [1024,2048): V tiles
  const int t = threadIdx.x;

  if (blk < 1024) {
    const int bh = blk >> 5, kt = blk & 31, b = bh >> 3;
    const int L = Lp[b];
    int NT = (L + 63) >> 6; if (NT < 1) NT = 1;
    if (kt >= NT) return;
    if (t < 64) {
      int j = kt * 64 + t;
      ridx[t] = (j < L) ? idxp[(size_t)b * S_LEN + j] : -1;
    }
    __syncthreads();
    const float* srcB = Kg + (size_t)bh * SD;
    char* dst = (char*)wsK + (size_t)blk * 8192;
#pragma unroll
    for (int i = 0; i < 2; ++i) {
      int task = t + 256 * i;        // 512 granules: row 0..63 x j 0..7
      int row = task >> 3, j = task & 7;
      int sr = ridx[row];
      half8_t h;
      if (sr >= 0) {
        const float* src = srcB + (size_t)sr * D_DIM + 8 * j;
        float4 lo = *(const float4*)(src);
        float4 hi = *(const float4*)(src + 4);
        fp16x2 p0 = __builtin_amdgcn_cvt_pkrtz(lo.x, lo.y);
        fp16x2 p1 = __builtin_amdgcn_cvt_pkrtz(lo.z, lo.w);
        fp16x2 p2 = __builtin_amdgcn_cvt_pkrtz(hi.x, hi.y);
        fp16x2 p3 = __builtin_amdgcn_cvt_pkrtz(hi.z, hi.w);
        h[0] = (_Float16)p0[0]; h[1] = (_Float16)p0[1];
        h[2] = (_Float16)p1[0]; h[3] = (_Float16)p1[1];
        h[4] = (_Float16)p2[0]; h[5] = (_Float16)p2[1];
        h[6] = (_Float16)p3[0]; h[7] = (_Float16)p3[1];
      } else {
#pragma unroll
        for (int e = 0; e < 8; ++e) h[e] = (_Float16)0.0f;
      }
      *(half8_t*)(dst + row * 128 + ((16 * j) ^ ((row & 7) << 4))) = h;
    }
  } else {
    const int vb = blk - 1024;
    const int bh = vb >> 5, kt = vb & 31, b = bh >> 3;
    const int L = Lp[b];
    int NT = (L + 63) >> 6; if (NT < 1) NT = 1;
    if (kt >= NT) return;
    if (t < 64) {
      int j = kt * 64 + t;
      ridx[t] = (j < L) ? idxp[(size_t)b * S_LEN + j] : -1;
    }
    __syncthreads();
    const float* srcB = Vg + (size_t)bh * SD;
    // gathered, coalesced-per-row load of the 64x64 f32 V tile
#pragma unroll
    for (int i = 0; i < 4; ++i) {
      int r = (t >> 4) + 16 * i, c4 = t & 15;
      int sr = ridx[r];
      float4 val = make_float4(0.f, 0.f, 0.f, 0.f);
      if (sr >= 0) val = *(const float4*)(srcB + (size_t)sr * D_DIM + c4 * 4);
      *(float4*)&vt[r][c4 * 4] = val;
    }
    __syncthreads();
    char* dst = (char*)wsV + (size_t)vb * 8192;
#pragma unroll
    for (int i = 0; i < 4; ++i) {
      int task = t + 256 * i;        // 1024 granules: drow 0..63 x j2 0..15
      int drow = task >> 4, j2 = task & 15, k0 = 4 * j2;
      float a = vt[k0][drow], b2 = vt[k0 + 1][drow];
      float cc = vt[k0 + 2][drow], d = vt[k0 + 3][drow];
      fp16x2 h0 = __builtin_amdgcn_cvt_pkrtz(a, b2);
      fp16x2 h1 = __builtin_amdgcn_cvt_pkrtz(cc, d);
      half4_t h;
      h[0] = (_Float16)h0[0]; h[1] = (_Float16)h0[1];
      h[2] = (_Float16)h1[0]; h[3] = (_Float16)h1[1];
      *(half4_t*)(dst + drow * 128 + ((8 * j2) ^ ((drow & 15) << 3))) = h;
    }
  }
}

// ============================================================================
// MAIN: round-5 body (proven 61.4us @ 32 iters) on compacted keys: NT ~ 17
// iterations, zero mask VALU, pure-DMA staging, lazy max, in-register P->PV,
// l-sum via ones/keep MFMA, K/V frags shared by 2 q-groups.
// ============================================================================
__global__ __launch_bounds__(256, 2)
void fattn_dma(const float* __restrict__ Qg, const _Float16* __restrict__ wsK,
               const _Float16* __restrict__ wsV, const int* __restrict__ Lp,
               float* __restrict__ Og) {
  __shared__ __align__(16) char smem[36864];
  // K dbuf 2x8192 [0,16384); V dbuf 2x8192 [16384,32768)
  float* Osh = (float*)smem;   // epilogue reuse (34816B)

  const int t = threadIdx.x;
  const int w = t >> 6;
  const int lane = t & 63;
  const int g = lane >> 4;
  const int c = lane & 15;

  const int bh = blockIdx.x & 31;   // bh fast: ws pinned to one XCD's L2
  const int qt = blockIdx.x >> 5;
  const int qb = qt * 128;

  const float* Qb = Qg + (size_t)bh * SD;
  float*       Ob = Og + (size_t)bh * SD;

  const int L = Lp[bh >> 3];        // kept-key count for this batch
  int NT = (L + 63) >> 6; if (NT < 1) NT = 1;

  // ---- tail keep-fragment: A[row][k=4g+e] = (key j < L) ? 1 : 0 ----
  half4_t kAtail[4];
#pragma unroll
  for (int mt = 0; mt < 4; ++mt)
#pragma unroll
    for (int e = 0; e < 4; ++e) {
      int j = (NT - 1) * 64 + 16 * mt + 4 * g + e;
      kAtail[mt][e] = (_Float16)((j < L) ? 1.0f : 0.0f);
    }

  // ---- Q^T B-frags; fold 1/8 * log2(e) ----
  const float qscale = 0.125f * 1.44269504088896340736f;
  half8_t qf[2][2];
#pragma unroll
  for (int h = 0; h < 2; ++h) {
    const float* qp = Qb + (size_t)(qb + 32 * w + 16 * h + c) * D_DIM + 8 * g;
#pragma unroll
    for (int ks = 0; ks < 2; ++ks) {
      float4 lo = *(const float4*)(qp + 32 * ks);
      float4 hi = *(const float4*)(qp + 32 * ks + 4);
      fp16x2 p0 = __builtin_amdgcn_cvt_pkrtz(lo.x * qscale, lo.y * qscale);
      fp16x2 p1 = __builtin_amdgcn_cvt_pkrtz(lo.z * qscale, lo.w * qscale);
      fp16x2 p2 = __builtin_amdgcn_cvt_pkrtz(hi.x * qscale, hi.y * qscale);
      fp16x2 p3 = __builtin_amdgcn_cvt_pkrtz(hi.z * qscale, hi.w * qscale);
      half8_t hh;
      hh[0] = (_Float16)p0[0]; hh[1] = (_Float16)p0[1];
      hh[2] = (_Float16)p1[0]; hh[3] = (_Float16)p1[1];
      hh[4] = (_Float16)p2[0]; hh[5] = (_Float16)p2[1];
      hh[6] = (_Float16)p3[0]; hh[7] = (_Float16)p3[1];
      qf[h][ks] = hh;
    }
  }

  // ---- DMA staging: per wave, 2KB of K + 2KB of V (4 x 16B/lane issues) ----
  const size_t tile_base0 = (size_t)bh * 32 * 8192;
  auto dma = [&](int buf, int kt) {
    const char* gK = (const char*)wsK + tile_base0 + (size_t)kt * 8192 +
                     w * 2048 + lane * 16;
    const char* gV = (const char*)wsV + tile_base0 + (size_t)kt * 8192 +
                     w * 2048 + lane * 16;
    char* lK = smem + 8192 * buf + w * 2048;
    char* lV = smem + 16384 + 8192 * buf + w * 2048;
    __builtin_amdgcn_global_load_lds((const float*)gK, (float*)lK, 16, 0, 0);
    __builtin_amdgcn_global_load_lds((const float*)(gK + 1024), (float*)(lK + 1024), 16, 0, 0);
    __builtin_amdgcn_global_load_lds((const float*)gV, (float*)lV, 16, 0, 0);
    __builtin_amdgcn_global_load_lds((const float*)(gV + 1024), (float*)(lV + 1024), 16, 0, 0);
  };

  f32x4 acc[2][4];
  f32x4 accl[2];
#pragma unroll
  for (int h = 0; h < 2; ++h) {
#pragma unroll
    for (int j = 0; j < 4; ++j) accl[h][j] = 0.f;
#pragma unroll
    for (int i = 0; i < 4; ++i)
#pragma unroll
      for (int j = 0; j < 4; ++j) acc[h][i][j] = 0.f;
  }
  float mrun[2] = {-1e30f, -1e30f};

  half4_t ones4;
  ones4[0] = (_Float16)1.0f; ones4[1] = (_Float16)1.0f;
  ones4[2] = (_Float16)1.0f; ones4[3] = (_Float16)1.0f;

  // loop-invariant swizzled frag byte-offsets (per lane)
  const int kxor = (c & 7) << 4;
  const int vxor = c << 3;

  dma(0, 0);
  __syncthreads();   // drains vmcnt: tile 0 resident

  for (int kt = 0; kt < NT; ++kt) {
    const int cur = kt & 1;
    if (kt < NT - 1) dma(cur ^ 1, kt + 1);   // in flight under compute

    const char* Kc = smem + 8192 * cur;
    const char* Vc = smem + 16384 + 8192 * cur;

    // ---- S^T = K . Q^T for both q-groups; K frag read ONCE ----
    f32x4 sT[2][4];
    __builtin_amdgcn_s_setprio(1);
#pragma unroll
    for (int mt = 0; mt < 4; ++mt) {
      f32x4 z0, z1;
#pragma unroll
      for (int j = 0; j < 4; ++j) { z0[j] = 0.f; z1[j] = 0.f; }
#pragma unroll
      for (int ks = 0; ks < 2; ++ks) {
        half8_t kf = *(const half8_t*)(Kc + (16 * mt + c) * 128 +
                                       ((ks * 64 + g * 16) ^ kxor));
        z0 = __builtin_amdgcn_mfma_f32_16x16x32_f16(kf, qf[0][ks], z0, 0, 0, 0);
        z1 = __builtin_amdgcn_mfma_f32_16x16x32_f16(kf, qf[1][ks], z1, 0, 0, 0);
      }
      sT[0][mt] = z0;
      sT[1][mt] = z1;
    }
    __builtin_amdgcn_s_setprio(0);

    // ---- V A-frags (K=16 PV), shared by both groups ----
    half4_t vf[4][4];  // [d-tile][k-step]
#pragma unroll
    for (int dt = 0; dt < 4; ++dt)
#pragma unroll
      for (int mtk = 0; mtk < 4; ++mtk)
        vf[dt][mtk] = *(const half4_t*)(Vc + (16 * dt + c) * 128 +
                                        ((32 * mtk + 8 * g) ^ vxor));

    // ---- lazy max: per-lane local max only in the common path ----
    float tl[2];
#pragma unroll
    for (int h = 0; h < 2; ++h) {
      float tm0 = fmaxf(fmaxf(sT[h][0][0], sT[h][0][1]),
                        fmaxf(sT[h][0][2], sT[h][0][3]));
      float tm1 = fmaxf(fmaxf(sT[h][1][0], sT[h][1][1]),
                        fmaxf(sT[h][1][2], sT[h][1][3]));
      float tm2 = fmaxf(fmaxf(sT[h][2][0], sT[h][2][1]),
                        fmaxf(sT[h][2][2], sT[h][2][3]));
      float tm3 = fmaxf(fmaxf(sT[h][3][0], sT[h][3][1]),
                        fmaxf(sT[h][3][2], sT[h][3][3]));
      tl[h] = fmaxf(fmaxf(tm0, tm1), fmaxf(tm2, tm3));
    }
    int ok0 = __all(tl[0] <= mrun[0] + THR);
    int ok1 = __all(tl[1] <= mrun[1] + THR);
    if (!(ok0 & ok1)) {
      // rare: exact row-max update + alpha rescale (wave-uniform branch)
#pragma unroll
      for (int h = 0; h < 2; ++h) {
        float tmax = tl[h];
        tmax = fmaxf(tmax, __shfl_xor(tmax, 16));
        tmax = fmaxf(tmax, __shfl_xor(tmax, 32));
        float mnew = fmaxf(mrun[h], tmax);
        float alpha = __builtin_amdgcn_exp2f(mrun[h] - mnew);
        mrun[h] = mnew;
        accl[h][0] *= alpha; accl[h][1] *= alpha;
        accl[h][2] *= alpha; accl[h][3] *= alpha;
#pragma unroll
        for (int mt = 0; mt < 4; ++mt) {
          acc[h][mt][0] *= alpha; acc[h][mt][1] *= alpha;
          acc[h][mt][2] *= alpha; acc[h][mt][3] *= alpha;
        }
      }
    }

    // ---- exp + in-register pack + PV; l-sum via ones/keep MFMA ----
    const int isTail = (kt == NT - 1);
    __builtin_amdgcn_s_setprio(1);
#pragma unroll
    for (int h = 0; h < 2; ++h) {
#pragma unroll
      for (int mt = 0; mt < 4; ++mt) {
        float pv0 = __builtin_amdgcn_exp2f(sT[h][mt][0] - mrun[h]);
        float pv1 = __builtin_amdgcn_exp2f(sT[h][mt][1] - mrun[h]);
        float pv2 = __builtin_amdgcn_exp2f(sT[h][mt][2] - mrun[h]);
        float pv3 = __builtin_amdgcn_exp2f(sT[h][mt][3] - mrun[h]);
        fp16x2 p01 = __builtin_amdgcn_cvt_pkrtz(pv0, pv1);
        fp16x2 p23 = __builtin_amdgcn_cvt_pkrtz(pv2, pv3);
        half4_t pf;
        pf[0] = (_Float16)p01[0]; pf[1] = (_Float16)p01[1];
        pf[2] = (_Float16)p23[0]; pf[3] = (_Float16)p23[1];
        half4_t ka = isTail ? kAtail[mt] : ones4;
        accl[h] = __builtin_amdgcn_mfma_f32_16x16x16f16(ka, pf, accl[h], 0, 0, 0);
#pragma unroll
        for (int dt = 0; dt < 4; ++dt)
          acc[h][dt] = __builtin_amdgcn_mfma_f32_16x16x16f16(vf[dt][mt], pf,
                                                             acc[h][dt], 0, 0, 0);
      }
    }
    __builtin_amdgcn_s_setprio(0);

    __syncthreads();  // drains vmcnt (DMA kt+1 done) + lgkm; guards swap
  }

  // ---- epilogue: /l, transpose O^T -> O via LDS, coalesced stores ----
#pragma unroll
  for (int h = 0; h < 2; ++h) {
    float denom = accl[h][0];   // keep-MFMA replicates l over rows
    float linv = (denom != 0.f) ? 1.f / denom : 0.f;
#pragma unroll
    for (int mt = 0; mt < 4; ++mt)
#pragma unroll
      for (int r = 0; r < 4; ++r)
        Osh[(32 * w + 16 * h + c) * LDO + 16 * mt + 4 * g + r] = acc[h][mt][r] * linv;
  }
  __syncthreads();
  {
    int f8 = t & 7;
#pragma unroll
    for (int i = 0; i < 4; ++i) {
      int q = (t >> 3) + 32 * i;
#pragma unroll
      for (int j = 0; j < 2; ++j) {
        int c4 = f8 + 8 * j;
        f32x4 o = *(f32x4*)(Osh + q * LDO + c4 * 4);
        *(float4*)(Ob + (size_t)(qb + q) * D_DIM + c4 * 4) =
            make_float4(o.x, o.y, o.z, o.w);
      }
    }
  }
}

// ============================================================================
// FALLBACK (round-3 kernel, 87us) — used only if ws_size < WS_NEED.
// ============================================================================
__global__ __launch_bounds__(256, 2)
void fattn_fb(const float* __restrict__ Qg, const float* __restrict__ Kg,
              const float* __restrict__ Vg, const int* __restrict__ Mg,
              float* __restrict__ Og) {
  __shared__ __align__(16) char smem[45056];
  float* Msh = (float*)(smem + 36864);
  float* Osh = (float*)smem;

  const int t = threadIdx.x;
  const int w = t >> 6;
  const int lane = t & 63;
  const int g = lane >> 4;
  const int c = lane & 15;

  const int bh = blockIdx.x & 31;
  const int qt = blockIdx.x >> 5;
  const int qb = qt * 128;

  const float* Qb = Qg + (size_t)bh * SD;
  const float* Kb = Kg + (size_t)bh * SD;
  const float* Vb = Vg + (size_t)bh * SD;
  const int*   Mb = Mg + (size_t)(bh >> 3) * S_LEN;
  float*       Ob = Og + (size_t)bh * SD;

  {
    int4 m0 = *(const int4*)(Mb + 8 * t);
    int4 m1 = *(const int4*)(Mb + 8 * t + 4);
    float4 f0, f1;
    f0.x = (float)(m0.x - 1) * 1e30f; f0.y = (float)(m0.y - 1) * 1e30f;
    f0.z = (float)(m0.z - 1) * 1e30f; f0.w = (float)(m0.w - 1) * 1e30f;
    f1.x = (float)(m1.x - 1) * 1e30f; f1.y = (float)(m1.y - 1) * 1e30f;
    f1.z = (float)(m1.z - 1) * 1e30f; f1.w = (float)(m1.w - 1) * 1e30f;
    *(float4*)(Msh + 8 * t) = f0;
    *(float4*)(Msh + 8 * t + 4) = f1;
  }

  const float qscale = 0.125f * 1.44269504088896340736f;
  half8_t qf[2][2];
#pragma unroll
  for (int h = 0; h < 2; ++h) {
    const float* qp = Qb + (size_t)(qb + 32 * w + 16 * h + c) * D_DIM + 8 * g;
#pragma unroll
    for (int ks = 0; ks < 2; ++ks) {
      float4 lo = *(const float4*)(qp + 32 * ks);
      float4 hi = *(const float4*)(qp + 32 * ks + 4);
      fp16x2 p0 = __builtin_amdgcn_cvt_pkrtz(lo.x * qscale, lo.y * qscale);
      fp16x2 p1 = __builtin_amdgcn_cvt_pkrtz(lo.z * qscale, lo.w * qscale);
      fp16x2 p2 = __builtin_amdgcn_cvt_pkrtz(hi.x * qscale, hi.y * qscale);
      fp16x2 p3 = __builtin_amdgcn_cvt_pkrtz(hi.z * qscale, hi.w * qscale);
      half8_t hh;
      hh[0] = (_Float16)p0[0]; hh[1] = (_Float16)p0[1];
      hh[2] = (_Float16)p1[0]; hh[3] = (_Float16)p1[1];
      hh[4] = (_Float16)p2[0]; hh[5] = (_Float16)p2[1];
      hh[6] = (_Float16)p3[0]; hh[7] = (_Float16)p3[1];
      qf[h][ks] = hh;
    }
  }

  const int krow0 = t >> 4;
  const int kc4   = t & 15;
  const int vp    = t >> 3;
  const int vkpl  = t & 7;

  float4 kr[4];
  float2 vr[8];
  auto prefetch = [&](int kb2) {
#pragma unroll
    for (int it = 0; it < 4; ++it)
      kr[it] = *(const float4*)(Kb + (size_t)(kb2 + krow0 + 16 * it) * D_DIM + kc4 * 4);
#pragma unroll
    for (int kc = 0; kc < 4; ++kc) {
      const float* vpp = Vb + (size_t)(kb2 + 2 * (vkpl + 8 * kc)) * D_DIM + 2 * vp;
      vr[2 * kc]     = *(const float2*)(vpp);
      vr[2 * kc + 1] = *(const float2*)(vpp + D_DIM);
    }
  };
  auto stage = [&](int buf) {
    _Float16* Kd = (_Float16*)(smem + 9216 * buf);
    _Float16* Vd = (_Float16*)(smem + 18432 + 9216 * buf);
#pragma unroll
    for (int it = 0; it < 4; ++it) {
      fp16x2 a  = __builtin_amdgcn_cvt_pkrtz(kr[it].x, kr[it].y);
      fp16x2 b2 = __builtin_amdgcn_cvt_pkrtz(kr[it].z, kr[it].w);
      half4_t h;
      h[0] = (_Float16)a[0]; h[1] = (_Float16)a[1];
      h[2] = (_Float16)b2[0]; h[3] = (_Float16)b2[1];
      *(half4_t*)(Kd + (krow0 + 16 * it) * LDK + kc4 * 4) = h;
    }
#pragma unroll
    for (int kc = 0; kc < 4; ++kc) {
      int kp = vkpl + 8 * kc;
      fp16x2 h0 = __builtin_amdgcn_cvt_pkrtz(vr[2 * kc].x, vr[2 * kc + 1].x);
      fp16x2 h1 = __builtin_amdgcn_cvt_pkrtz(vr[2 * kc].y, vr[2 * kc + 1].y);
      half2_t g0; g0[0] = (_Float16)h0[0]; g0[1] = (_Float16)h0[1];
      half2_t g1; g1[0] = (_Float16)h1[0]; g1[1] = (_Float16)h1[1];
      *(half2_t*)(Vd + (2 * vp) * LDK + 2 * kp) = g0;
      *(half2_t*)(Vd + (2 * vp + 1) * LDK + 2 * kp) = g1;
    }
  };

  f32x4 acc[2][4];
  f32x4 accl[2];
#pragma unroll
  for (int h = 0; h < 2; ++h) {
#pragma unroll
    for (int j = 0; j < 4; ++j) accl[h][j] = 0.f;
#pragma unroll
    for (int i = 0; i < 4; ++i)
#pragma unroll
      for (int j = 0; j < 4; ++j) acc[h][i][j] = 0.f;
  }
  float mrun[2] = {-1e30f, -1e30f};

  half4_t ones4;
  ones4[0] = (_Float16)1.0f; ones4[1] = (_Float16)1.0f;
  ones4[2] = (_Float16)1.0f; ones4[3] = (_Float16)1.0f;

  prefetch(0);
  stage(0);
  prefetch(BC);
  __syncthreads();

  for (int kt = 0; kt < 32; ++kt) {
    const int kb = kt * BC;
    const int cur = kt & 1;

    if (kt < 31) stage(cur ^ 1);
    if (kt < 30) prefetch(kb + 2 * BC);

    const _Float16* Kc = (const _Float16*)(smem + 9216 * cur);
    const _Float16* Vc = (const _Float16*)(smem + 18432 + 9216 * cur);

    f32x4 sT[2][4];
    __builtin_amdgcn_s_setprio(1);
#pragma unroll
    for (int mt = 0; mt < 4; ++mt) {
      f32x4 z0, z1;
#pragma unroll
      for (int j = 0; j < 4; ++j) { z0[j] = 0.f; z1[j] = 0.f; }
#pragma unroll
      for (int ks = 0; ks < 2; ++ks) {
        half8_t kf = *(half8_t*)(Kc + (16 * mt + c) * LDK + ks * 32 + 8 * g);
        z0 = __builtin_amdgcn_mfma_f32_16x16x32_f16(kf, qf[0][ks], z0, 0, 0, 0);
        z1 = __builtin_amdgcn_mfma_f32_16x16x32_f16(kf, qf[1][ks], z1, 0, 0, 0);
      }
      sT[0][mt] = z0;
      sT[1][mt] = z1;
    }
    __builtin_amdgcn_s_setprio(0);

    half4_t vf[4][4];
#pragma unroll
    for (int dt = 0; dt < 4; ++dt)
#pragma unroll
      for (int kst = 0; kst < 4; ++kst)
        vf[dt][kst] = *(half4_t*)(Vc + (16 * dt + c) * LDK + 16 * kst + 4 * g);

    f32x4 mvf[4];
#pragma unroll
    for (int mt = 0; mt < 4; ++mt)
      mvf[mt] = *(const f32x4*)(Msh + kb + 16 * mt + 4 * g);
#pragma unroll
    for (int h = 0; h < 2; ++h)
#pragma unroll
      for (int mt = 0; mt < 4; ++mt)
#pragma unroll
        for (int r = 0; r < 4; ++r) sT[h][mt][r] += mvf[mt][r];

    float tl[2];
#pragma unroll
    for (int h = 0; h < 2; ++h) {
      float tm0 = fmaxf(fmaxf(sT[h][0][0], sT[h][0][1]),
                        fmaxf(sT[h][0][2], sT[h][0][3]));
      float tm1 = fmaxf(fmaxf(sT[h][1][0], sT[h][1][1]),
                        fmaxf(sT[h][1][2], sT[h][1][3]));
      float tm2 = fmaxf(fmaxf(sT[h][2][0], sT[h][2][1]),
                        fmaxf(sT[h][2][2], sT[h][2][3]));
      float tm3 = fmaxf(fmaxf(sT[h][3][0], sT[h][3][1]),
                        fmaxf(sT[h][3][2], sT[h][3][3]));
      tl[h] = fmaxf(fmaxf(tm0, tm1), fmaxf(tm2, tm3));
    }
    int ok0 = __all(tl[0] <= mrun[0] + THR);
    int ok1 = __all(tl[1] <= mrun[1] + THR);
    if (!(ok0 & ok1)) {
#pragma unroll
      for (int h = 0; h < 2; ++h) {
        float tmax = tl[h];
        tmax = fmaxf(tmax, __shfl_xor(tmax, 16));
        tmax = fmaxf(tmax, __shfl_xor(tmax, 32));
        float mnew = fmaxf(mrun[h], tmax);
        float alpha = __builtin_amdgcn_exp2f(mrun[h] - mnew);
        mrun[h] = mnew;
        accl[h][0] *= alpha; accl[h][1] *= alpha;
        accl[h][2] *= alpha; accl[h][3] *= alpha;
#pragma unroll
        for (int mt = 0; mt < 4; ++mt) {
          acc[h][mt][0] *= alpha; acc[h][mt][1] *= alpha;
          acc[h][mt][2] *= alpha; acc[h][mt][3] *= alpha;
        }
      }
    }

    __builtin_amdgcn_s_setprio(1);
#pragma unroll
    for (int h = 0; h < 2; ++h) {
#pragma unroll
      for (int mt = 0; mt < 4; ++mt) {
        float pv0 = __builtin_amdgcn_exp2f(sT[h][mt][0] - mrun[h]);
        float pv1 = __builtin_amdgcn_exp2f(sT[h][mt][1] - mrun[h]);
        float pv2 = __builtin_amdgcn_exp2f(sT[h][mt][2] - mrun[h]);
        float pv3 = __builtin_amdgcn_exp2f(sT[h][mt][3] - mrun[h]);
        fp16x2 p01 = __builtin_amdgcn_cvt_pkrtz(pv0, pv1);
        fp16x2 p23 = __builtin_amdgcn_cvt_pkrtz(pv2, pv3);
        half4_t pf;
        pf[0] = (_Float16)p01[0]; pf[1] = (_Float16)p01[1];
        pf[2] = (_Float16)p23[0]; pf[3] = (_Float16)p23[1];
        accl[h] = __builtin_amdgcn_mfma_f32_16x16x16f16(ones4, pf, accl[h], 0, 0, 0);
#pragma unroll
        for (int dt = 0; dt < 4; ++dt)
          acc[h][dt] = __builtin_amdgcn_mfma_f32_16x16x16f16(vf[dt][mt], pf,
                                                             acc[h][dt], 0, 0, 0);
      }
    }
    __builtin_amdgcn_s_setprio(0);

    __syncthreads();
  }

#pragma unroll
  for (int h = 0; h < 2; ++h) {
    float linv = 1.f / accl[h][0];
#pragma unroll
    for (int mt = 0; mt < 4; ++mt)
#pragma unroll
      for (int r = 0; r < 4; ++r)
        Osh[(32 * w + 16 * h + c) * LDO + 16 * mt + 4 * g + r] = acc[h][mt][r] * linv;
  }
  __syncthreads();
  {
    int f8 = t & 7;
#pragma unroll
    for (int i = 0; i < 4; ++i) {
      int q = (t >> 3) + 32 * i;
#pragma unroll
      for (int j = 0; j < 2; ++j) {
        int c4 = f8 + 8 * j;
        f32x4 o = *(f32x4*)(Osh + q * LDO + c4 * 4);
        *(float4*)(Ob + (size_t)(qb + q) * D_DIM + c4 * 4) =
            make_float4(o.x, o.y, o.z, o.w);
      }
    }
  }
}

extern "C" void kernel_launch(void* const* d_in, const int* in_sizes, int n_in,
                              void* d_out, int out_size, void* d_ws, size_t ws_size,
                              hipStream_t stream) {
  (void)in_sizes; (void)n_in; (void)out_size;
  const float* Q = (const float*)d_in[0];
  const float* K = (const float*)d_in[1];
  const float* V = (const float*)d_in[2];
  const int*   M = (const int*)d_in[3];
  float* O = (float*)d_out;

  if (ws_size >= WS_NEED && d_ws != nullptr) {
    _Float16* wsK = (_Float16*)d_ws;
    _Float16* wsV = (_Float16*)((char*)d_ws + (size_t)8 * 1024 * 1024);
    int* idxp = (int*)((char*)d_ws + (size_t)16 * 1024 * 1024);
    int* Lp = idxp + 4 * S_LEN;
    compact_kernel<<<dim3(4), dim3(256), 0, stream>>>(M, idxp, Lp);
    prep_kernel<<<dim3(2048), dim3(256), 0, stream>>>(K, V, idxp, Lp, wsK, wsV);
    fattn_dma<<<dim3(32 * 16), dim3(256), 0, stream>>>(Q, wsK, wsV, Lp, O);
  } else {
    fattn_fb<<<dim3(32 * 16), dim3(256), 0, stream>>>(Q, K, V, M, O);
  }
}